// Round 12
// baseline (351.903 us; speedup 1.0000x reference)
//
#include <hip/hip_runtime.h>
#include <hip/hip_bf16.h>

typedef __hip_bfloat16 bf16;

#define B_     8
#define N_     64
#define H_     512
#define HEADS_ 8
#define SP_    64
#define L_     4
static constexpr float INV_SCALE = 0.044194173824159216f; // 1/sqrt(512)

typedef __attribute__((ext_vector_type(8))) short short8;
typedef __attribute__((ext_vector_type(4))) float f32x4;

__device__ __forceinline__ void unpack8(uint4 u, float* f) {
    f[0] = __uint_as_float(u.x << 16); f[1] = __uint_as_float(u.x & 0xffff0000u);
    f[2] = __uint_as_float(u.y << 16); f[3] = __uint_as_float(u.y & 0xffff0000u);
    f[4] = __uint_as_float(u.z << 16); f[5] = __uint_as_float(u.z & 0xffff0000u);
    f[6] = __uint_as_float(u.w << 16); f[7] = __uint_as_float(u.w & 0xffff0000u);
}

__device__ __forceinline__ bf16 f2bf(float v) { return __float2bfloat16(v); }

__device__ __forceinline__ uint4 pack8bf(float4 a, float4 b) {
    __align__(16) bf16 t[8];
    t[0] = f2bf(a.x); t[1] = f2bf(a.y); t[2] = f2bf(a.z); t[3] = f2bf(a.w);
    t[4] = f2bf(b.x); t[5] = f2bf(b.y); t[6] = f2bf(b.z); t[7] = f2bf(b.w);
    return *(const uint4*)t;
}

// 64-dim dot of fp32 q-slice (shared) with a bf16 row (L2-resident basis table)
__device__ __forceinline__ float dot64(const float* __restrict__ qq,
                                       const bf16* __restrict__ row) {
    float acc = 0.f;
    #pragma unroll
    for (int t = 0; t < 8; ++t) {
        uint4 u = ((const uint4*)row)[t];
        float f[8];
        unpack8(u, f);
        const float* q8 = &qq[t * 8];
        acc += q8[0]*f[0] + q8[1]*f[1] + q8[2]*f[2] + q8[3]*f[3]
             + q8[4]*f[4] + q8[5]*f[5] + q8[6]*f[6] + q8[7]*f[7];
    }
    return acc;
}

#define RSTR 80

// ------------------------------------------------------------ GEMM body (64-tile)
// EPI: 0 = fp32 out, 1 = fp32 + residual, 2 = relu->bf16, 3 = bf16
template <int EPI>
__device__ __forceinline__ void gemm64_body(char* lds,
        const bf16* __restrict__ A, const bf16* __restrict__ Bt,
        void* __restrict__ Cv, const float* __restrict__ R,
        int M, int N, int K, int bx, int by, int kbeg, int kend) {
    char* As = lds;
    char* Bs = lds + 2 * 64 * RSTR;
    const int tid = threadIdx.x;
    const int bm = bx * 64, bn = by * 64;
    const int w = tid >> 6, lane = tid & 63;
    const int wr = (w >> 1) * 32, wc = (w & 1) * 32;
    const int m0 = lane & 15, q4 = lane >> 4;

    f32x4 acc[2][2] = {};

    const int rA = tid >> 3;
    const int cA = tid & 7;
    const int ksP = cA >> 2;
    const int cB = (cA & 3) * 16;
    const int cE = cA * 8;

    for (int k0 = kbeg; k0 < kend; k0 += 64) {
        uint4 a0 = *(const uint4*)(A  + (size_t)(bm + rA) * K + k0 + cE);
        uint4 a1 = *(const uint4*)(A  + (size_t)(bm + rA + 32) * K + k0 + cE);
        uint4 b0 = *(const uint4*)(Bt + (size_t)(bn + rA) * K + k0 + cE);
        uint4 b1 = *(const uint4*)(Bt + (size_t)(bn + rA + 32) * K + k0 + cE);
        __syncthreads();
        *(uint4*)(As + ksP * (64 * RSTR) + rA * RSTR + cB) = a0;
        *(uint4*)(As + ksP * (64 * RSTR) + (rA + 32) * RSTR + cB) = a1;
        *(uint4*)(Bs + ksP * (64 * RSTR) + rA * RSTR + cB) = b0;
        *(uint4*)(Bs + ksP * (64 * RSTR) + (rA + 32) * RSTR + cB) = b1;
        __syncthreads();
        short8 af[2][2], bfr[2][2];
        #pragma unroll
        for (int ks = 0; ks < 2; ++ks)
            #pragma unroll
            for (int t = 0; t < 2; ++t) {
                af[ks][t]  = *(const short8*)(As + ks * (64 * RSTR) + (wr + t * 16 + m0) * RSTR + q4 * 16);
                bfr[ks][t] = *(const short8*)(Bs + ks * (64 * RSTR) + (wc + t * 16 + m0) * RSTR + q4 * 16);
            }
        #pragma unroll
        for (int ks = 0; ks < 2; ++ks)
            #pragma unroll
            for (int mt = 0; mt < 2; ++mt)
                #pragma unroll
                for (int nt = 0; nt < 2; ++nt)
                    acc[mt][nt] = __builtin_amdgcn_mfma_f32_16x16x32_bf16(
                        af[ks][mt], bfr[ks][nt], acc[mt][nt], 0, 0, 0);
    }

    if (EPI <= 1) {
        float* C = (float*)Cv;
        #pragma unroll
        for (int mt = 0; mt < 2; ++mt)
            #pragma unroll
            for (int i = 0; i < 4; ++i) {
                int row = bm + wr + mt * 16 + q4 * 4 + i;
                #pragma unroll
                for (int nt = 0; nt < 2; ++nt) {
                    int col = bn + wc + nt * 16 + m0;
                    float v = acc[mt][nt][i];
                    if (EPI == 1) v += R[(size_t)row * N + col];
                    C[(size_t)row * N + col] = v;
                }
            }
    } else {
        bf16* C = (bf16*)Cv;
        #pragma unroll
        for (int mt = 0; mt < 2; ++mt)
            #pragma unroll
            for (int i = 0; i < 4; ++i) {
                int row = bm + wr + mt * 16 + q4 * 4 + i;
                #pragma unroll
                for (int nt = 0; nt < 2; ++nt) {
                    int col = bn + wc + nt * 16 + m0;
                    float v = acc[mt][nt][i];
                    if (EPI == 2) v = fmaxf(v, 0.0f);
                    C[(size_t)row * N + col] = __float2bfloat16(v);
                }
            }
    }
}

template <int EPI, bool SPLIT>
__launch_bounds__(256)
__global__ void mfma_gemm_s(const bf16* __restrict__ A, const bf16* __restrict__ Bt,
                            void* __restrict__ Cv, const float* __restrict__ R,
                            int M, int N, int K) {
    __shared__ __align__(16) char lds[4 * 64 * RSTR];
    int kbeg = 0, kend = K;
    const bf16* B2 = Bt;
    void* C2 = Cv;
    if (SPLIT) {
        int ks = K / gridDim.z;
        kbeg = blockIdx.z * ks;
        kend = kbeg + ks;
        C2 = (void*)((float*)Cv + (size_t)blockIdx.z * M * N);
        gemm64_body<0>(lds, A, B2, C2, nullptr, M, N, K, blockIdx.x, blockIdx.y, kbeg, kend);
    } else {
        B2 = Bt + (size_t)blockIdx.z * N * K;
        if (EPI <= 1) C2 = (void*)((float*)Cv + (size_t)blockIdx.z * M * N);
        gemm64_body<EPI>(lds, A, B2, C2, R, M, N, K, blockIdx.x, blockIdx.y, kbeg, kend);
    }
}

// ------------------------------------------------ device bodies (shared pieces)

// u_bf[b,i,h,k] = sum_d q[b,i,h*64+d] * Wew3[k,h*64+d]
__device__ __forceinline__ void ugemm_body(char* lds, const float* __restrict__ q,
        const bf16* __restrict__ wc3, bf16* __restrict__ ubf, int h, int mb, int nb) {
    char* As = lds;
    char* Bs = lds + 2 * 64 * RSTR;
    const int tid = threadIdx.x;
    const int w = tid >> 6, lane = tid & 63;
    const int wr = (w >> 1) * 32, wc = (w & 1) * 32;
    const int m0 = lane & 15, q4 = lane >> 4;
    const int rA = tid >> 3;
    const int cA = tid & 7;
    const int ksP = cA >> 2;
    const int cB = (cA & 3) * 16;
    const int cE = cA * 8;

    const float* Aq = q + (size_t)(mb * 64) * 512 + h * 64;
    const bf16*  Bt = wc3 + (size_t)(nb * 64) * 512 + h * 64;

    float4 fa0 = *(const float4*)(Aq + (size_t)rA * 512 + cE);
    float4 fa1 = *(const float4*)(Aq + (size_t)rA * 512 + cE + 4);
    float4 fb0 = *(const float4*)(Aq + (size_t)(rA + 32) * 512 + cE);
    float4 fb1 = *(const float4*)(Aq + (size_t)(rA + 32) * 512 + cE + 4);
    uint4 b0 = *(const uint4*)(Bt + (size_t)rA * 512 + cE);
    uint4 b1 = *(const uint4*)(Bt + (size_t)(rA + 32) * 512 + cE);
    uint4 a0 = pack8bf(fa0, fa1);
    uint4 a1 = pack8bf(fb0, fb1);
    *(uint4*)(As + ksP * (64 * RSTR) + rA * RSTR + cB) = a0;
    *(uint4*)(As + ksP * (64 * RSTR) + (rA + 32) * RSTR + cB) = a1;
    *(uint4*)(Bs + ksP * (64 * RSTR) + rA * RSTR + cB) = b0;
    *(uint4*)(Bs + ksP * (64 * RSTR) + (rA + 32) * RSTR + cB) = b1;
    __syncthreads();

    f32x4 acc[2][2] = {};
    short8 af[2][2], bfr[2][2];
    #pragma unroll
    for (int ks = 0; ks < 2; ++ks)
        #pragma unroll
        for (int t = 0; t < 2; ++t) {
            af[ks][t]  = *(const short8*)(As + ks * (64 * RSTR) + (wr + t * 16 + m0) * RSTR + q4 * 16);
            bfr[ks][t] = *(const short8*)(Bs + ks * (64 * RSTR) + (wc + t * 16 + m0) * RSTR + q4 * 16);
        }
    #pragma unroll
    for (int ks = 0; ks < 2; ++ks)
        #pragma unroll
        for (int mt = 0; mt < 2; ++mt)
            #pragma unroll
            for (int nt = 0; nt < 2; ++nt)
                acc[mt][nt] = __builtin_amdgcn_mfma_f32_16x16x32_bf16(
                    af[ks][mt], bfr[ks][nt], acc[mt][nt], 0, 0, 0);

    #pragma unroll
    for (int mt = 0; mt < 2; ++mt)
        #pragma unroll
        for (int i = 0; i < 4; ++i) {
            int row = mb * 64 + wr + mt * 16 + q4 * 4 + i;
            #pragma unroll
            for (int nt = 0; nt < 2; ++nt) {
                int col = nb * 64 + wc + nt * 16 + m0;
                ubf[(size_t)row * 4096 + h * 512 + col] = f2bf(acc[mt][nt][i]);
            }
        }
}

// edge softmax coeffs for l=0 from Gram tables (G0 in gbuf slot 5, TEE in slot 6)
__device__ __forceinline__ void coeff0_vals(const float* __restrict__ gbuf,
        int b, int i, int j, int t, float* c) {
    const float* G0  = gbuf + 5 * 32768 + (size_t)b * 4096;
    const float* TEE = gbuf + 6 * 32768;
    float s0 = TEE[t * 64 + t];
    float s1 = G0[t * 64 + i];
    float s2 = G0[t * 64 + j];
    float t0 = s0 * INV_SCALE, t1 = s1 * INV_SCALE, t2 = s2 * INV_SCALE;
    float m = fmaxf(t0, fmaxf(t1, t2));
    float e0 = expf(t0 - m), e1 = expf(t1 - m), e2 = expf(t2 - m);
    float inv = 1.0f / (e0 + e1 + e2);
    c[0] = e0 * inv; c[1] = e1 * inv; c[2] = e2 * inv;
}

// edge softmax coeffs from l=1 Gram tables
__device__ __forceinline__ void coeff1_vals(const float* __restrict__ gbuf,
        float c0, float c1, float c2, int b, int i, int j, int t, float* c) {
    const float* TXX = gbuf + 0 * 32768 + (size_t)b * 4096;
    const float* TEX = gbuf + 1 * 32768 + (size_t)b * 4096;
    const float* TXx = gbuf + 2 * 32768 + (size_t)b * 4096;
    const float* TEx = gbuf + 3 * 32768 + (size_t)b * 4096;
    const float* TEE = gbuf + 4 * 32768 + (size_t)b * 4096;
    float s1 = c0 * TEx[t * 64 + i] + c1 * TXx[i * 64 + i] + c2 * TXx[j * 64 + i];
    float s2 = c0 * TEx[t * 64 + j] + c1 * TXx[i * 64 + j] + c2 * TXx[j * 64 + j];
    float s0 = c0 * c0 * TEE[t * 64 + t] + c1 * c1 * TXX[i * 64 + i] + c2 * c2 * TXX[j * 64 + j]
             + 2.f * c0 * c1 * TEX[t * 64 + i] + 2.f * c0 * c2 * TEX[t * 64 + j]
             + 2.f * c1 * c2 * TXX[i * 64 + j];
    float t0 = s0 * INV_SCALE, t1 = s1 * INV_SCALE, t2 = s2 * INV_SCALE;
    float m = fmaxf(t0, fmaxf(t1, t2));
    float e0 = expf(t0 - m), e1 = expf(t1 - m), e2 = expf(t2 - m);
    float inv = 1.0f / (e0 + e1 + e2);
    c[0] = e0 * inv; c[1] = e1 * inv; c[2] = e2 * inv;
}

// edge softmax coeffs from l=2 Gram tables
__device__ __forceinline__ void coeff2_body(const int* __restrict__ adj,
        const float* __restrict__ c0a, const float* __restrict__ c1a, const float* __restrict__ c2a,
        const float* __restrict__ c0b, const float* __restrict__ c1b, const float* __restrict__ c2b,
        const float* __restrict__ gbuf, int row, int j,
        float* __restrict__ w0o, float* __restrict__ w1o, float* __restrict__ w2o) {
    int b = row >> 6, i = row & 63;
    int p = row * 64 + j;
    int t = adj[p];
    const float* TXX = gbuf + 0 * 32768 + (size_t)b * 4096;
    const float* TXY = gbuf + 1 * 32768 + (size_t)b * 4096;
    const float* TYY = gbuf + 2 * 32768 + (size_t)b * 4096;
    const float* TEX = gbuf + 3 * 32768 + (size_t)b * 4096;
    const float* TEY = gbuf + 4 * 32768 + (size_t)b * 4096;
    const float* TEE = gbuf + 5 * 32768 + (size_t)b * 4096;
    const float* TXx = gbuf + 6 * 32768 + (size_t)b * 4096;
    const float* TYx = gbuf + 7 * 32768 + (size_t)b * 4096;
    const float* TEx = gbuf + 8 * 32768 + (size_t)b * 4096;
    float a0 = c0b[p];
    float AE = a0 * c0a[p], Aa = a0 * c1a[p], Ab = a0 * c2a[p];
    float Ac = c1b[p], Ad = c2b[p];
    float s1 = AE * TEx[t * 64 + i] + Aa * TXx[i * 64 + i] + Ab * TXx[j * 64 + i]
             + Ac * TYx[i * 64 + i] + Ad * TYx[j * 64 + i];
    float s2 = AE * TEx[t * 64 + j] + Aa * TXx[i * 64 + j] + Ab * TXx[j * 64 + j]
             + Ac * TYx[i * 64 + j] + Ad * TYx[j * 64 + j];
    float s0 = AE * AE * TEE[t * 64 + t] + Aa * Aa * TXX[i * 64 + i] + Ab * Ab * TXX[j * 64 + j]
             + Ac * Ac * TYY[i * 64 + i] + Ad * Ad * TYY[j * 64 + j]
             + 2.f * AE * Aa * TEX[t * 64 + i] + 2.f * AE * Ab * TEX[t * 64 + j]
             + 2.f * AE * Ac * TEY[t * 64 + i] + 2.f * AE * Ad * TEY[t * 64 + j]
             + 2.f * Aa * Ab * TXX[i * 64 + j]
             + 2.f * Aa * Ac * TXY[i * 64 + i] + 2.f * Aa * Ad * TXY[i * 64 + j]
             + 2.f * Ab * Ac * TXY[j * 64 + i] + 2.f * Ab * Ad * TXY[j * 64 + j]
             + 2.f * Ac * Ad * TYY[i * 64 + j];
    float t0 = s0 * INV_SCALE, t1 = s1 * INV_SCALE, t2 = s2 * INV_SCALE;
    float m = fmaxf(t0, fmaxf(t1, t2));
    float e0 = expf(t0 - m), e1 = expf(t1 - m), e2 = expf(t2 - m);
    float inv = 1.0f / (e0 + e1 + e2);
    w0o[p] = e0 * inv;
    w1o[p] = e1 * inv;
    w2o[p] = e2 * inv;
}

// ------------------------------------------------ merged one-shot setup kernel
// grid: [0,512) embed | [512,1152) sq transpose (2x 64x64 tiles/block)
//       [1152,2176) rect transpose (2x tiles/block) | [2176,2304) bond_bf | [2304,2432) cast_w3
__launch_bounds__(256)
__global__ void setup_kernel(const int* __restrict__ ids, const float* __restrict__ atom_emb,
                             const float* __restrict__ bond_emb,
                             const float* __restrict__ Wq, const float* __restrict__ Wk,
                             const float* __restrict__ Wv, const float* __restrict__ Wew,
                             const float* __restrict__ Wst,
                             const float* __restrict__ Wf1, const float* __restrict__ Wf2,
                             float* __restrict__ xn, bf16* __restrict__ xn_bf,
                             bf16* __restrict__ qkvt, bf16* __restrict__ ewt,
                             bf16* __restrict__ stackt,
                             bf16* __restrict__ f1t, bf16* __restrict__ f2t,
                             bf16* __restrict__ bond_bf, bf16* __restrict__ wc3) {
    __shared__ __align__(16) float smem[64 * 65];   // 16.6 KB; reused by all sections
    const size_t KN = (size_t)H_ * H_;
    int bid = blockIdx.x;
    int tid = threadIdx.x;

    if (bid < 512) {
        // ---- embed + LN
        int row = bid;
        const float* r = atom_emb + (size_t)ids[row] * H_;
        float x0 = r[tid], x1 = r[tid + 256];
        float s = x0 + x1, sq = x0 * x0 + x1 * x1;
        #pragma unroll
        for (int off = 32; off; off >>= 1) {
            s  += __shfl_xor(s,  off);
            sq += __shfl_xor(sq, off);
        }
        int w = tid >> 6;
        if ((tid & 63) == 0) { smem[w] = s; smem[4 + w] = sq; }
        __syncthreads();
        float S = smem[0] + smem[1] + smem[2] + smem[3];
        float Q = smem[4] + smem[5] + smem[6] + smem[7];
        float mean = S * (1.0f / H_);
        float var  = Q * (1.0f / H_) - mean * mean;
        float inv  = rsqrtf(var + 1e-5f);
        float y0 = (x0 - mean) * inv, y1 = (x1 - mean) * inv;
        xn[(size_t)row * H_ + tid]       = y0;
        xn[(size_t)row * H_ + tid + 256] = y1;
        xn_bf[(size_t)row * H_ + tid]       = f2bf(y0);
        xn_bf[(size_t)row * H_ + tid + 256] = f2bf(y1);
    } else if (bid < 2176) {
        // ---- 64x64 fp32 -> bf16 transpose tiles, 2 tiles per block
        for (int sub = 0; sub < 2; ++sub) {
            const float* W; bf16* Wt; int K, N, kb, nb;
            if (bid < 1152) {
                int idx = (bid - 512) * 2 + sub;     // [0,1280)
                int z = idx >> 6, rem = idx & 63;
                kb = rem & 7; nb = rem >> 3;
                K = 512; N = 512;
                if (z < 12) {
                    int sss = z >> 2, l = z & 3;
                    W  = (sss == 0 ? Wq : sss == 1 ? Wk : Wv) + (size_t)l * KN;
                    Wt = qkvt + (size_t)l * 3 * KN + (size_t)sss * KN;
                } else if (z < 16) {
                    int l = z - 12;
                    W = Wew + (size_t)l * KN; Wt = ewt + (size_t)l * KN;
                } else {
                    int l = z - 16;
                    W = Wst + (size_t)l * KN; Wt = stackt + (size_t)l * KN;
                }
            } else {
                int idx = (bid - 1152) * 2 + sub;    // [0,2048)
                int z = idx >> 8;                    // 0..7
                int idx2 = idx & 255;
                const size_t KN4 = (size_t)4 * H_ * H_;
                if (z < 4) {
                    W = Wf1 + (size_t)z * KN4; Wt = f1t + (size_t)z * KN4; K = 512; N = 2048;
                    kb = idx2 & 7; nb = idx2 >> 3;
                } else {
                    W = Wf2 + (size_t)(z - 4) * KN4; Wt = f2t + (size_t)(z - 4) * KN4; K = 2048; N = 512;
                    kb = idx2 >> 3; nb = idx2 & 7;
                }
            }
            int k0 = kb * 64, n0 = nb * 64;
            float (*tt)[65] = (float(*)[65])smem;
            int rr = tid >> 4, c4 = (tid & 15) * 4;
            if (sub) __syncthreads();   // protect smem reuse between tiles
            #pragma unroll
            for (int it = 0; it < 4; ++it) {
                float4 v = *(const float4*)(W + (size_t)(k0 + rr + it * 16) * N + n0 + c4);
                tt[rr + it * 16][c4 + 0] = v.x;
                tt[rr + it * 16][c4 + 1] = v.y;
                tt[rr + it * 16][c4 + 2] = v.z;
                tt[rr + it * 16][c4 + 3] = v.w;
            }
            __syncthreads();
            int nr = tid >> 3, k8 = (tid & 7) * 8;
            #pragma unroll
            for (int it = 0; it < 2; ++it) {
                int nn = nr + it * 32;
                __align__(16) bf16 ob[8];
                #pragma unroll
                for (int e = 0; e < 8; ++e)
                    ob[e] = f2bf(tt[k8 + e][nn]);
                *(uint4*)(Wt + (size_t)(n0 + nn) * K + k0 + k8) = *(const uint4*)ob;
            }
        }
    } else if (bid < 2304) {
        // ---- bond_bf: bf16 cast of bond_emb rows <8; rows 8..63 zero (pad for E0 GEMM)
        int idx = bid - 2176;
        int t = idx >> 1;
        int c = (idx & 1) * 256 + tid;
        bond_bf[t * 512 + c] = (t < 8) ? f2bf(bond_emb[t * 512 + c]) : f2bf(0.0f);
    } else {
        // ---- cast Wew3 -> bf16
        int idx = bid - 2304;
        int gid = idx * 256 + tid;
        const float4* p = (const float4*)(Wew + 3 * KN + (size_t)gid * 8);
        float4 a = p[0], b = p[1];
        *(uint4*)(wc3 + (size_t)gid * 8) = pack8bf(a, b);
    }
}

// ------------------------------------------------ l=0 head: qkv + E0 MFMA GEMM
// grid: [0,192) qkv (z=bid>>6, mb=(bid>>3)&7, by=bid&7) | [192,200) E0 = bond_bf @ ewt0
__launch_bounds__(256)
__global__ void qkv0_e0(const bf16* __restrict__ xn_bf, const bf16* __restrict__ qkvt,
                        float* __restrict__ qkv,
                        const bf16* __restrict__ bond_bf, const bf16* __restrict__ ewt0,
                        bf16* __restrict__ E0) {
    __shared__ __align__(16) char lds[4 * 64 * RSTR];
    int bid = blockIdx.x;
    if (bid < 192) {
        int z = bid >> 6, rem = bid & 63;
        int mb = rem >> 3, by = rem & 7;
        gemm64_body<0>(lds, xn_bf, qkvt + (size_t)z * 262144,
                       qkv + (size_t)z * 262144, nullptr, 512, 512, 512, mb, by, 0, 512);
    } else {
        gemm64_body<3>(lds, bond_bf, ewt0, E0, nullptr, 64, 512, 512,
                       0, bid - 192, 0, 512);
    }
}

// ------------------------------------------------ l=1 head: basis1 + qkv + l=0 Gram tables
// grid: [0,264) gemm (bx=bid>>3, by=bid&7) | [264,272) G0_b = E0 @ x_b^T | [272] TEE = E0 @ E0^T
__launch_bounds__(256)
__global__ void basis1_qkv_g0(const bf16* __restrict__ x_bf, const bf16* __restrict__ E0,
                              const bf16* __restrict__ ewt1,
                              bf16* __restrict__ xw1, bf16* __restrict__ e0w1,
                              const bf16* __restrict__ xn_bf, const bf16* __restrict__ qkvt_l,
                              float* __restrict__ qkv, float* __restrict__ gbuf) {
    __shared__ __align__(16) char lds[4 * 64 * RSTR];
    int bid = blockIdx.x;
    if (bid < 264) {
        int bx = bid >> 3, by = bid & 7;
        if (bx < 8)
            gemm64_body<3>(lds, x_bf, ewt1, xw1, nullptr, 512, 512, 512, bx, by, 0, 512);
        else if (bx == 8)
            gemm64_body<3>(lds, E0, ewt1, e0w1, nullptr, 64, 512, 512, 0, by, 0, 512);
        else {
            int tq = bx - 9;
            int z = tq >> 3, mb = tq & 7;
            gemm64_body<0>(lds, xn_bf, qkvt_l + (size_t)z * 262144,
                           qkv + (size_t)z * 262144, nullptr, 512, 512, 512, mb, by, 0, 512);
        }
    } else if (bid < 272) {
        int b = bid - 264;
        gemm64_body<0>(lds, E0, x_bf + (size_t)b * 32768,
                       gbuf + 5 * 32768 + (size_t)b * 4096, nullptr,
                       64, 64, 512, 0, 0, 0, 512);
    } else {
        gemm64_body<0>(lds, E0, E0, gbuf + 6 * 32768, nullptr,
                       64, 64, 512, 0, 0, 0, 512);
    }
}

// ------------------------------------------------ l=2 head: basis2 + qkv + gram1
// grid: [0,328) gemm | [328,368) gram1 (b=k&7, z=k>>3)
__launch_bounds__(256)
__global__ void basis2_qkv_g1(const bf16* __restrict__ xw1, const bf16* __restrict__ x_bf,
                              const bf16* __restrict__ e0w1, const bf16* __restrict__ ewt2,
                              bf16* __restrict__ xw12, bf16* __restrict__ x2w2,
                              bf16* __restrict__ e0w12,
                              const bf16* __restrict__ xn_bf, const bf16* __restrict__ qkvt_l,
                              float* __restrict__ qkv, float* __restrict__ gbuf) {
    __shared__ __align__(16) char lds[4 * 64 * RSTR];
    int bid = blockIdx.x;
    if (bid < 328) {
        int bx = bid >> 3, by = bid & 7;
        if (bx < 8)
            gemm64_body<3>(lds, xw1, ewt2, xw12, nullptr, 512, 512, 512, bx, by, 0, 512);
        else if (bx < 16)
            gemm64_body<3>(lds, x_bf, ewt2, x2w2, nullptr, 512, 512, 512, bx - 8, by, 0, 512);
        else if (bx == 16)
            gemm64_body<3>(lds, e0w1, ewt2, e0w12, nullptr, 64, 512, 512, 0, by, 0, 512);
        else {
            int tq = bx - 17;
            int z = tq >> 3, mb = tq & 7;
            gemm64_body<0>(lds, xn_bf, qkvt_l + (size_t)z * 262144,
                           qkv + (size_t)z * 262144, nullptr, 512, 512, 512, mb, by, 0, 512);
        }
    } else {
        int k = bid - 328;
        int b = k & 7, z = k >> 3;
        size_t ob = (size_t)b * 32768;
        const bf16 *A, *Bt;
        switch (z) {
            case 0: A = xw1 + ob; Bt = xw1 + ob; break;
            case 1: A = e0w1;     Bt = xw1 + ob; break;
            case 2: A = xw1 + ob; Bt = x_bf + ob; break;
            case 3: A = e0w1;     Bt = x_bf + ob; break;
            default: A = e0w1;    Bt = e0w1;     break;
        }
        float* C = gbuf + (size_t)z * 32768 + (size_t)b * 4096;
        gemm64_body<0>(lds, A, Bt, C, nullptr, 64, 64, 512, 0, 0, 0, 512);
    }
}

// ------------------------------------------------ l=3 head: qkv + gram2
// grid: [0,192) qkv (z=bid>>6, mb=(bid>>3)&7, by=bid&7) | [192,264) gram2
__launch_bounds__(256)
__global__ void l3qkv_g2(const bf16* __restrict__ xn_bf, const bf16* __restrict__ qkvt_l,
                         float* __restrict__ qkv,
                         const bf16* __restrict__ xw12, const bf16* __restrict__ x2w2,
                         const bf16* __restrict__ e0w12, const bf16* __restrict__ x_bf,
                         float* __restrict__ gbuf) {
    __shared__ __align__(16) char lds[4 * 64 * RSTR];
    int bid = blockIdx.x;
    if (bid < 192) {
        int z = bid >> 6, rem = bid & 63;
        int mb = rem >> 3, by = rem & 7;
        gemm64_body<0>(lds, xn_bf, qkvt_l + (size_t)z * 262144,
                       qkv + (size_t)z * 262144, nullptr, 512, 512, 512, mb, by, 0, 512);
    } else {
        int k = bid - 192;
        int b = k & 7, z = k >> 3;
        size_t ob = (size_t)b * 32768;
        const bf16 *A, *Bt;
        switch (z) {
            case 0: A = xw12 + ob; Bt = xw12 + ob; break;
            case 1: A = xw12 + ob; Bt = x2w2 + ob; break;
            case 2: A = x2w2 + ob; Bt = x2w2 + ob; break;
            case 3: A = e0w12;     Bt = xw12 + ob; break;
            case 4: A = e0w12;     Bt = x2w2 + ob; break;
            case 5: A = e0w12;     Bt = e0w12;     break;
            case 6: A = xw12 + ob; Bt = x_bf + ob; break;
            case 7: A = x2w2 + ob; Bt = x_bf + ob; break;
            default: A = e0w12;    Bt = x_bf + ob; break;
        }
        float* C = gbuf + (size_t)z * 32768 + (size_t)b * 4096;
        gemm64_body<0>(lds, A, Bt, C, nullptr, 64, 64, 512, 0, 0, 0, 512);
    }
}

// ------------------------------------------------ l=3: u_gemm + coeff2
// grid: [0,512) u (h=bid>>6, mb=(bid>>3)&7, nb=bid&7) | [512,576) coeff2 (8 rows each)
__launch_bounds__(256)
__global__ void u_c2(const float* __restrict__ q, const bf16* __restrict__ wc3,
                     bf16* __restrict__ ubf,
                     const int* __restrict__ adj,
                     const float* __restrict__ c0a, const float* __restrict__ c1a,
                     const float* __restrict__ c2a,
                     const float* __restrict__ c0b, const float* __restrict__ c1b,
                     const float* __restrict__ c2b,
                     const float* __restrict__ gbuf,
                     float* __restrict__ w0o, float* __restrict__ w1o,
                     float* __restrict__ w2o) {
    __shared__ __align__(16) char lds[4 * 64 * RSTR];
    int bid = blockIdx.x;
    if (bid < 512) {
        int h = bid >> 6, mb = (bid >> 3) & 7, nb = bid & 7;
        ugemm_body(lds, q, wc3, ubf, h, mb, nb);
    } else {
        int k = bid - 512;
        int tid = threadIdx.x;
        int j = tid & 63;
        #pragma unroll
        for (int pass = 0; pass < 2; ++pass) {
            int row = k * 8 + pass * 4 + (tid >> 6);
            coeff2_body(adj, c0a, c1a, c2a, c0b, c1b, c2b, gbuf, row, j, w0o, w1o, w2o);
        }
    }
}

// M-tables: for each b, U_b (512 rows (i,h) x 512 k) @ basis_b^T (64 x 512)
__launch_bounds__(256)
__global__ void mbuf_gemm(const bf16* __restrict__ ubf, const bf16* __restrict__ xw12,
                          const bf16* __restrict__ x2w2, const bf16* __restrict__ x_bf,
                          const bf16* __restrict__ e0w12,
                          float* __restrict__ MX, float* __restrict__ MY,
                          float* __restrict__ MZ, float* __restrict__ DE) {
    __shared__ __align__(16) char lds[4 * 64 * RSTR];
    int b = blockIdx.x, mt = blockIdx.y, z = blockIdx.z;
    const bf16* A = ubf + (size_t)b * 512 * 512;
    const bf16* Bt;
    float* C;
    if (z == 0)      { Bt = xw12 + (size_t)b * 64 * 512; C = MX + (size_t)b * 512 * 64; }
    else if (z == 1) { Bt = x2w2 + (size_t)b * 64 * 512; C = MY + (size_t)b * 512 * 64; }
    else if (z == 2) { Bt = x_bf + (size_t)b * 64 * 512; C = MZ + (size_t)b * 512 * 64; }
    else             { Bt = e0w12;                        C = DE + (size_t)b * 512 * 64; }
    gemm64_body<0>(lds, A, Bt, C, nullptr, 512, 64, 512, mt, 0, 0, 512);
}

// ---------------------- split-K reduce + residual + LN variants
__global__ void reduce_stack_ln(const float* __restrict__ part, const float* __restrict__ base,
                                float* __restrict__ resid, bf16* __restrict__ ffin_bf) {
    const int MN = 512 * H_;
    int row = blockIdx.x;
    int tid = threadIdx.x;
    size_t b0 = (size_t)row * H_;
    float v0 = base[b0 + tid], v1 = base[b0 + tid + 256];
    #pragma unroll
    for (int s = 0; s < 4; ++s) {
        v0 += part[(size_t)s * MN + b0 + tid];
        v1 += part[(size_t)s * MN + b0 + tid + 256];
    }
    resid[b0 + tid] = v0;
    resid[b0 + tid + 256] = v1;
    float s = v0 + v1, sq = v0 * v0 + v1 * v1;
    #pragma unroll
    for (int off = 32; off; off >>= 1) {
        s  += __shfl_xor(s,  off);
        sq += __shfl_xor(sq, off);
    }
    __shared__ float ls[4], lq[4];
    int w = tid >> 6;
    if ((tid & 63) == 0) { ls[w] = s; lq[w] = sq; }
    __syncthreads();
    float S = ls[0] + ls[1] + ls[2] + ls[3];
    float Q = lq[0] + lq[1] + lq[2] + lq[3];
    float mean = S * (1.0f / H_);
    float var  = Q * (1.0f / H_) - mean * mean;
    float inv  = rsqrtf(var + 1e-5f);
    ffin_bf[b0 + tid]       = f2bf((v0 - mean) * inv);
    ffin_bf[b0 + tid + 256] = f2bf((v1 - mean) * inv);
}

template <bool DO_LN>
__global__ void reduce_ln_kernel(const float* __restrict__ part, const float* __restrict__ resid,
                                 float* __restrict__ x, bf16* __restrict__ x_bf,
                                 float* __restrict__ xn, bf16* __restrict__ xn_bf) {
    const int MN = 512 * H_;
    int row = blockIdx.x;
    int tid = threadIdx.x;
    size_t base = (size_t)row * H_;
    float v0 = resid[base + tid], v1 = resid[base + tid + 256];
    #pragma unroll
    for (int s = 0; s < 4; ++s) {
        v0 += part[(size_t)s * MN + base + tid];
        v1 += part[(size_t)s * MN + base + tid + 256];
    }
    x[base + tid] = v0;
    x[base + tid + 256] = v1;
    x_bf[base + tid]       = f2bf(v0);
    x_bf[base + tid + 256] = f2bf(v1);
    if (DO_LN) {
        float s = v0 + v1, sq = v0 * v0 + v1 * v1;
        #pragma unroll
        for (int off = 32; off; off >>= 1) {
            s  += __shfl_xor(s,  off);
            sq += __shfl_xor(sq, off);
        }
        __shared__ float ls[4], lq[4];
        int w = tid >> 6;
        if ((tid & 63) == 0) { ls[w] = s; lq[w] = sq; }
        __syncthreads();
        float S = ls[0] + ls[1] + ls[2] + ls[3];
        float Q = lq[0] + lq[1] + lq[2] + lq[3];
        float mean = S * (1.0f / H_);
        float var  = Q * (1.0f / H_) - mean * mean;
        float inv  = rsqrtf(var + 1e-5f);
        float y0 = (v0 - mean) * inv, y1 = (v1 - mean) * inv;
        xn[base + tid]       = y0;
        xn[base + tid + 256] = y1;
        xn_bf[base + tid]       = f2bf(y0);
        xn_bf[base + tid + 256] = f2bf(y1);
    }
}

// ---------------------------------------------------------------- attention
// l=0: w-row gathered from E0[adj[pair]] (8-row table, L1-resident)
template <bool GATHER>
__global__ void attn_kernel(const float* __restrict__ qkv, const bf16* __restrict__ ew,
                            const int* __restrict__ adj, bf16* __restrict__ o) {
    const float* q = qkv;
    const float* k = qkv + (size_t)512 * H_;
    const float* v = qkv + (size_t)1024 * H_;
    int bi = blockIdx.x;
    int b  = bi >> 6;
    int ty = threadIdx.y;
    int h  = blockIdx.y * 4 + ty;
    int lane = threadIdx.x;
    __shared__ float qs[4][64], as[4][64];
    qs[ty][lane] = q[(size_t)bi * H_ + h * 64 + lane];
    __syncthreads();

    int j = lane;
    int pair = bi * 64 + j;
    int aj = adj[pair];
    const float4* k4 = (const float4*)(k + (size_t)(b * 64 + j) * H_ + h * 64);
    const uint4*  w4 = (const uint4*)((GATHER ? ew + (size_t)aj * H_
                                              : ew + (size_t)pair * H_) + h * 64);
    float acc = 0.f;
    #pragma unroll
    for (int t = 0; t < 8; ++t) {
        uint4 wu = w4[t];
        float4 ka = k4[2 * t], kb = k4[2 * t + 1];
        float wf[8];
        unpack8(wu, wf);
        const float* qq = &qs[ty][t * 8];
        acc += qq[0] * (ka.x + wf[0]) + qq[1] * (ka.y + wf[1])
             + qq[2] * (ka.z + wf[2]) + qq[3] * (ka.w + wf[3])
             + qq[4] * (kb.x + wf[4]) + qq[5] * (kb.y + wf[5])
             + qq[6] * (kb.z + wf[6]) + qq[7] * (kb.w + wf[7]);
    }
    float logit = acc * INV_SCALE;
    if (aj <= 0) logit = -INFINITY;

    float m = logit;
    #pragma unroll
    for (int off = 32; off; off >>= 1) m = fmaxf(m, __shfl_xor(m, off));
    float p = expf(logit - m);
    float s = p;
    #pragma unroll
    for (int off = 32; off; off >>= 1) s += __shfl_xor(s, off);
    as[ty][lane] = p / s;
    __syncthreads();

    const float* vbase = v + (size_t)(b * 64) * H_ + h * 64;
    float oacc = 0.f;
    int d = lane;
    #pragma unroll 8
    for (int jj = 0; jj < 64; ++jj)
        oacc += as[ty][jj] * vbase[(size_t)jj * H_ + d];
    o[(size_t)bi * H_ + h * 64 + d] = __float2bfloat16(oacc);
}

// l=1/l=2: P-dots + edge coeffs computed INLINE (ptable kernels eliminated).
// MODE 1: coeffs from l=0 Gram tables (gbuf slots 5/6), writes cw*a.
// MODE 2: coeffs from gram1 tables (gbuf 0..4) + cw*a, writes cw*b.
template <int MODE>
__global__ void attn13_kernel(const float* __restrict__ qkv, const int* __restrict__ adj,
        const float* __restrict__ c0a, const float* __restrict__ c1a, const float* __restrict__ c2a,
        const bf16* __restrict__ BE, const bf16* __restrict__ BX, const bf16* __restrict__ BY,
        const float* __restrict__ gbuf,
        float* __restrict__ w0o, float* __restrict__ w1o, float* __restrict__ w2o,
        bf16* __restrict__ o) {
    const float* q = qkv;
    const float* k = qkv + (size_t)512 * H_;
    const float* v = qkv + (size_t)1024 * H_;
    int bi = blockIdx.x;
    int b  = bi >> 6, i = bi & 63;
    int ty = threadIdx.y;
    int h  = blockIdx.y * 4 + ty;
    int lane = threadIdx.x;
    __shared__ float qs[4][64], as[4][64];
    qs[ty][lane] = q[(size_t)bi * H_ + h * 64 + lane];
    __syncthreads();

    int j = lane;
    int p = bi * 64 + j;
    int t = adj[p];

    // inline edge-softmax coefficients
    float cc[3];
    if (MODE == 1) {
        coeff0_vals(gbuf, b, i, j, t, cc);
    } else {
        coeff1_vals(gbuf, c0a[p], c1a[p], c2a[p], b, i, j, t, cc);
    }
    if (blockIdx.y == 0 && ty == 0) {
        w0o[p] = cc[0]; w1o[p] = cc[1]; w2o[p] = cc[2];
    }

    // inline P-dots: q_i . basis rows (64-dim, head h slice)
    const float* qq = qs[ty];
    float pE  = dot64(qq, BE + (size_t)t * H_ + h * 64);
    float pXj = dot64(qq, BX + ((size_t)(b * 64 + j)) * H_ + h * 64);
    float pXi = __shfl(pXj, i);

    float acc;
    if (MODE == 1) {
        acc = cc[0] * pE + cc[1] * pXi + cc[2] * pXj;
    } else {
        float pYj = dot64(qq, BY + ((size_t)(b * 64 + j)) * H_ + h * 64);
        float pYi = __shfl(pYj, i);
        float a0 = cc[0];
        float AE = a0 * c0a[p], Aa = a0 * c1a[p], Ab = a0 * c2a[p];
        acc = AE * pE + Aa * pXi + Ab * pXj + cc[1] * pYi + cc[2] * pYj;
    }

    const float4* k4 = (const float4*)(k + (size_t)(b * 64 + j) * H_ + h * 64);
    #pragma unroll
    for (int tt = 0; tt < 8; ++tt) {
        float4 ka = k4[2 * tt], kb = k4[2 * tt + 1];
        const float* q8 = &qs[ty][tt * 8];
        acc += q8[0] * ka.x + q8[1] * ka.y + q8[2] * ka.z + q8[3] * ka.w
             + q8[4] * kb.x + q8[5] * kb.y + q8[6] * kb.z + q8[7] * kb.w;
    }
    float logit = acc * INV_SCALE;
    if (t <= 0) logit = -INFINITY;

    float m = logit;
    #pragma unroll
    for (int off = 32; off; off >>= 1) m = fmaxf(m, __shfl_xor(m, off));
    float pe = expf(logit - m);
    float s = pe;
    #pragma unroll
    for (int off = 32; off; off >>= 1) s += __shfl_xor(s, off);
    as[ty][lane] = pe / s;
    __syncthreads();

    const float* vbase = v + (size_t)(b * 64) * H_ + h * 64;
    float oacc = 0.f;
    int d = lane;
    #pragma unroll 8
    for (int jj = 0; jj < 64; ++jj)
        oacc += as[ty][jj] * vbase[(size_t)jj * H_ + d];
    o[(size_t)bi * H_ + h * 64 + d] = __float2bfloat16(oacc);
}

// l=3: w-term computed inline from M-tables + coeffs (s2_assemble fused in)
__global__ void attn3s2_kernel(const float* __restrict__ qkv, const int* __restrict__ adj,
        const float* __restrict__ c0a, const float* __restrict__ c1a, const float* __restrict__ c2a,
        const float* __restrict__ c0b, const float* __restrict__ c1b, const float* __restrict__ c2b,
        const float* __restrict__ v0c, const float* __restrict__ v1c, const float* __restrict__ v2c,
        const float* __restrict__ MX, const float* __restrict__ MY,
        const float* __restrict__ MZ, const float* __restrict__ DE,
        bf16* __restrict__ o) {
    const float* q = qkv;
    const float* k = qkv + (size_t)512 * H_;
    const float* v = qkv + (size_t)1024 * H_;
    int bi = blockIdx.x;
    int b  = bi >> 6, i = bi & 63;
    int ty = threadIdx.y;
    int h  = blockIdx.y * 4 + ty;
    int lane = threadIdx.x;
    __shared__ float qs[4][64], as[4][64];
    qs[ty][lane] = q[(size_t)bi * H_ + h * 64 + lane];
    __syncthreads();

    int j = lane;
    int p = bi * 64 + j;
    int t = adj[p];
    float v0 = v0c[p];
    float q0 = v0 * c0b[p];
    float AE = q0 * c0a[p], Aa = q0 * c1a[p], Ab = q0 * c2a[p];
    float Ac = v0 * c1b[p], Ad = v0 * c2b[p];
    float Ae = v1c[p], Af = v2c[p];
    size_t rb = ((size_t)b * 512 + i * 8 + h) * 64;
    float acc = AE * DE[rb + t]
              + Aa * MX[rb + i] + Ac * MY[rb + i] + Ae * MZ[rb + i]
              + Ab * MX[rb + j] + Ad * MY[rb + j] + Af * MZ[rb + j];

    const float4* k4 = (const float4*)(k + (size_t)(b * 64 + j) * H_ + h * 64);
    #pragma unroll
    for (int tt = 0; tt < 8; ++tt) {
        float4 ka = k4[2 * tt], kb = k4[2 * tt + 1];
        const float* qq = &qs[ty][tt * 8];
        acc += qq[0] * ka.x + qq[1] * ka.y + qq[2] * ka.z + qq[3] * ka.w
             + qq[4] * kb.x + qq[5] * kb.y + qq[6] * kb.z + qq[7] * kb.w;
    }
    float logit = acc * INV_SCALE;
    if (t <= 0) logit = -INFINITY;

    float m = logit;
    #pragma unroll
    for (int off = 32; off; off >>= 1) m = fmaxf(m, __shfl_xor(m, off));
    float pe = expf(logit - m);
    float s = pe;
    #pragma unroll
    for (int off = 32; off; off >>= 1) s += __shfl_xor(s, off);
    as[ty][lane] = pe / s;
    __syncthreads();

    const float* vbase = v + (size_t)(b * 64) * H_ + h * 64;
    float oacc = 0.f;
    int d = lane;
    #pragma unroll 8
    for (int jj = 0; jj < 64; ++jj)
        oacc += as[ty][jj] * vbase[(size_t)jj * H_ + d];
    o[(size_t)bi * H_ + h * 64 + d] = __float2bfloat16(oacc);
}

// ---------------------------------------------------------------- head
__global__ void cls_part_kernel(const float* __restrict__ x, const float* __restrict__ Wout,
                                float* __restrict__ clspart) {
    int b  = blockIdx.x;
    int cb = blockIdx.y;
    int ks = blockIdx.z;
    int tid = threadIdx.x;
    int c  = cb * 64 + (tid & 63);
    int kk = tid >> 6;
    const float* xr = x + (size_t)(b * 64) * H_;
    int h0 = ks * 128 + kk * 32;
    float acc = 0.f;
    #pragma unroll
    for (int h = 0; h < 32; ++h)
        acc += xr[h0 + h] * Wout[(size_t)(h0 + h) * H_ + c];
    __shared__ float red[4][64];
    red[kk][tid & 63] = acc;
    __syncthreads();
    if (tid < 64) {
        float v = red[0][tid] + red[1][tid] + red[2][tid] + red[3][tid];
        clspart[((size_t)ks * 8 + b) * H_ + cb * 64 + tid] = v;
    }
}

__global__ void cls_pred2_kernel(const float* __restrict__ clspart,
                                 const float* __restrict__ Wpred,
                                 const float* __restrict__ bpred,
                                 float* __restrict__ out) {
    int b = blockIdx.x;
    int tid = threadIdx.x;
    __shared__ float red0[4], red1[4];
    float a0 = 0.f, a1 = 0.f;
    #pragma unroll
    for (int t = 0; t < 2; ++t) {
        int c = tid + t * 256;
        float v = clspart[((size_t)0 * 8 + b) * H_ + c]
                + clspart[((size_t)1 * 8 + b) * H_ + c]
                + clspart[((size_t)2 * 8 + b) * H_ + c]
                + clspart[((size_t)3 * 8 + b) * H_ + c];
        float tv = tanhf(v);
        a0 += tv * Wpred[c * 2 + 0];
        a1 += tv * Wpred[c * 2 + 1];
    }
    #pragma unroll
    for (int off = 32; off; off >>= 1) {
        a0 += __shfl_xor(a0, off);
        a1 += __shfl_xor(a1, off);
    }
    int w = tid >> 6;
    if ((tid & 63) == 0) { red0[w] = a0; red1[w] = a1; }
    __syncthreads();
    if (tid == 0) {
        float s0 = red0[0] + red0[1] + red0[2] + red0[3] + bpred[0];
        float s1 = red1[0] + red1[1] + red1[2] + red1[3] + bpred[1];
        float m = fmaxf(s0, s1);
        float e0 = expf(s0 - m), e1 = expf(s1 - m);
        float inv = 1.0f / (e0 + e1);
        out[b * 2 + 0] = e0 * inv;
        out[b * 2 + 1] = e1 * inv;
    }
}

// ---------------------------------------------------------------- launch
extern "C" void kernel_launch(void* const* d_in, const int* in_sizes, int n_in,
                              void* d_out, int out_size, void* d_ws, size_t ws_size,
                              hipStream_t stream) {
    const int*   ids      = (const int*)d_in[0];
    const int*   adj      = (const int*)d_in[1];
    const float* atom_emb = (const float*)d_in[2];
    const float* bond_emb = (const float*)d_in[3];
    const float* Wq     = (const float*)d_in[4];
    const float* Wk     = (const float*)d_in[5];
    const float* Wv     = (const float*)d_in[6];
    const float* Wew    = (const float*)d_in[7];
    const float* Wstack = (const float*)d_in[8];
    const float* Wf1    = (const float*)d_in[9];
    const float* Wf2    = (const float*)d_in[10];
    const float* Wout   = (const float*)d_in[11];
    const float* Wpred  = (const float*)d_in[12];
    const float* bpred  = (const float*)d_in[13];

    char* ws = (char*)d_ws;
    size_t off = 0;
    auto alloc = [&](size_t bytes) {
        size_t o = off;
        off += (bytes + 255) & ~(size_t)255;
        return o;
    };
    const size_t ROWS  = (size_t)B_ * N_;
    const size_t PAIRS = (size_t)B_ * N_ * N_;
    const size_t KN    = (size_t)H_ * H_;

    float* x       = (float*)(ws + alloc(ROWS * H_ * 4));
    float* xn      = (float*)(ws + alloc(ROWS * H_ * 4));
    bf16*  xn_bf   = (bf16*) (ws + alloc(ROWS * H_ * 2));
    bf16*  x_bf    = (bf16*) (ws + alloc(ROWS * H_ * 2));
    float* qkv     = (float*)(ws + alloc(3 * ROWS * H_ * 4));
    bf16*  o_bf    = (bf16*) (ws + alloc(ROWS * H_ * 2));
    float* resid   = (float*)(ws + alloc(ROWS * H_ * 4));
    bf16*  ffin_bf = (bf16*) (ws + alloc(ROWS * H_ * 2));
    bf16*  ffh_bf  = (bf16*) (ws + alloc(ROWS * 4 * H_ * 2));
    float* part    = (float*)(ws + alloc(4 * ROWS * H_ * 4));
    float* clspart = (float*)(ws + alloc(4 * 8 * H_ * 4));
    bf16*  ubf     = (bf16*) (ws + alloc(ROWS * 8 * 512 * 2));           // 4 MB
    float* MX      = (float*)(ws + alloc((size_t)4096 * 64 * 4));        // 1 MB each
    float* MY      = (float*)(ws + alloc((size_t)4096 * 64 * 4));
    float* MZ      = (float*)(ws + alloc((size_t)4096 * 64 * 4));
    float* DE      = (float*)(ws + alloc((size_t)4096 * 64 * 4));
    float* gbuf    = (float*)(ws + alloc((size_t)9 * 8 * 4096 * 4));     // Gram tables (slots 5,6 reused for l=0)
    bf16*  wc3     = (bf16*) (ws + alloc(KN * 2));
    bf16*  bond_bf = (bf16*) (ws + alloc(64 * H_ * 2));      // bond_emb bf16, rows 8..63 zero
    bf16*  E0      = (bf16*) (ws + alloc(64 * H_ * 2));      // padded to 64 rows
    bf16*  e0w1    = (bf16*) (ws + alloc(64 * H_ * 2));
    bf16*  e0w12   = (bf16*) (ws + alloc(64 * H_ * 2));
    bf16*  xw1     = (bf16*) (ws + alloc(KN * 2));
    bf16*  xw12    = (bf16*) (ws + alloc(KN * 2));
    bf16*  x2w2    = (bf16*) (ws + alloc(KN * 2));
    float* cw      = (float*)(ws + alloc(9 * PAIRS * 4));    // edge softmax coeffs
    bf16*  qkvt    = (bf16*) (ws + alloc((size_t)L_ * 3 * KN * 2));
    bf16*  ewt     = (bf16*) (ws + alloc((size_t)L_ * KN * 2));
    bf16*  stackt  = (bf16*) (ws + alloc((size_t)L_ * KN * 2));
    bf16*  f1t     = (bf16*) (ws + alloc((size_t)L_ * 4 * KN * 2));
    bf16*  f2t     = (bf16*) (ws + alloc((size_t)L_ * 4 * KN * 2));
    (void)ws_size;

    float* cw0a = cw;
    float* cw1a = cw + PAIRS;
    float* cw2a = cw + 2 * PAIRS;
    float* cw0b = cw + 3 * PAIRS;
    float* cw1b = cw + 4 * PAIRS;
    float* cw2b = cw + 5 * PAIRS;
    float* cw0c = cw + 6 * PAIRS;
    float* cw1c = cw + 7 * PAIRS;
    float* cw2c = cw + 8 * PAIRS;

    // one-shot setup: embed+LN, weight transposes (2 tiles/block), bond_bf, Wew3 cast
    setup_kernel<<<2432, 256, 0, stream>>>(ids, atom_emb, bond_emb,
                                           Wq, Wk, Wv, Wew, Wstack, Wf1, Wf2,
                                           xn, xn_bf, qkvt, ewt, stackt, f1t, f2t,
                                           bond_bf, wc3);

    for (int l = 0; l < L_; ++l) {
        if (l == 0) {
            // qkv + E0 (E0 = bond_bf @ ewt0 via MFMA)
            qkv0_e0<<<200, 256, 0, stream>>>(xn_bf, qkvt, qkv, bond_bf, ewt, E0);
            attn_kernel<true><<<dim3(512, 2), dim3(64, 4), 0, stream>>>(qkv, E0, adj, o_bf);
        } else if (l == 1) {
            // basis1 + qkv + l=0 Gram tables (G0_b, TEE)
            basis1_qkv_g0<<<273, 256, 0, stream>>>(
                x_bf, E0, ewt + KN, xw1, e0w1, xn_bf, qkvt + (size_t)3 * KN, qkv, gbuf);
            // attn with inline P-dots + inline coeff0 (writes cw*a) -- ptable dispatch gone
            attn13_kernel<1><<<dim3(512, 2), dim3(64, 4), 0, stream>>>(
                qkv, adj, nullptr, nullptr, nullptr,
                e0w1, xw1, nullptr, gbuf, cw0a, cw1a, cw2a, o_bf);
        } else if (l == 2) {
            // basis2 + qkv + gram1
            basis2_qkv_g1<<<368, 256, 0, stream>>>(
                xw1, x_bf, e0w1, ewt + 2 * KN, xw12, x2w2, e0w12,
                xn_bf, qkvt + (size_t)6 * KN, qkv, gbuf);
            // attn with inline P-dots + inline coeff1 (writes cw*b) -- ptable dispatch gone
            attn13_kernel<2><<<dim3(512, 2), dim3(64, 4), 0, stream>>>(
                qkv, adj, cw0a, cw1a, cw2a,
                e0w12, xw12, x2w2, gbuf, cw0b, cw1b, cw2b, o_bf);
        } else {
            // qkv + gram2
            l3qkv_g2<<<264, 256, 0, stream>>>(
                xn_bf, qkvt + (size_t)9 * KN, qkv, xw12, x2w2, e0w12, x_bf, gbuf);
            // u + coeff2
            u_c2<<<576, 256, 0, stream>>>(
                qkv, wc3, ubf, adj, cw0a, cw1a, cw2a, cw0b, cw1b, cw2b,
                gbuf, cw0c, cw1c, cw2c);
            mbuf_gemm<<<dim3(8, 8, 4), 256, 0, stream>>>(ubf, xw12, x2w2, x_bf, e0w12,
                                                         MX, MY, MZ, DE);
            attn3s2_kernel<<<dim3(512, 2), dim3(64, 4), 0, stream>>>(
                qkv, adj, cw0a, cw1a, cw2a, cw0b, cw1b, cw2b, cw0c, cw1c, cw2c,
                MX, MY, MZ, DE, o_bf);
        }

        mfma_gemm_s<0, true><<<dim3(8, 8, 4), 256, 0, stream>>>(
            o_bf, stackt + (size_t)l * KN, part, nullptr, 512, 512, 512);
        reduce_stack_ln<<<512, 256, 0, stream>>>(part, xn, resid, ffin_bf);
        mfma_gemm_s<2, false><<<dim3(8, 32), 256, 0, stream>>>(
            ffin_bf, f1t + (size_t)l * 4 * KN, ffh_bf, nullptr, 512, 2048, 512);
        mfma_gemm_s<0, true><<<dim3(8, 8, 4), 256, 0, stream>>>(
            ffh_bf, f2t + (size_t)l * 4 * KN, part, nullptr, 512, 512, 2048);
        if (l < L_ - 1)
            reduce_ln_kernel<true><<<512, 256, 0, stream>>>(part, resid, x, x_bf, xn, xn_bf);
        else
            reduce_ln_kernel<false><<<512, 256, 0, stream>>>(part, resid, x, x_bf, xn, xn_bf);
    }

    cls_part_kernel<<<dim3(8, 8, 4), 256, 0, stream>>>(x, Wout, clspart);
    cls_pred2_kernel<<<8, 256, 0, stream>>>(clspart, Wpred, bpred, (float*)d_out);
}

// Round 13
// 335.192 us; speedup vs baseline: 1.0499x; 1.0499x over previous
//
#include <hip/hip_runtime.h>
#include <hip/hip_bf16.h>

typedef __hip_bfloat16 bf16;

#define B_     8
#define N_     64
#define H_     512
#define HEADS_ 8
#define SP_    64
#define L_     4
static constexpr float INV_SCALE = 0.044194173824159216f; // 1/sqrt(512)

typedef __attribute__((ext_vector_type(8))) short short8;
typedef __attribute__((ext_vector_type(4))) float f32x4;

__device__ __forceinline__ void unpack8(uint4 u, float* f) {
    f[0] = __uint_as_float(u.x << 16); f[1] = __uint_as_float(u.x & 0xffff0000u);
    f[2] = __uint_as_float(u.y << 16); f[3] = __uint_as_float(u.y & 0xffff0000u);
    f[4] = __uint_as_float(u.z << 16); f[5] = __uint_as_float(u.z & 0xffff0000u);
    f[6] = __uint_as_float(u.w << 16); f[7] = __uint_as_float(u.w & 0xffff0000u);
}

__device__ __forceinline__ bf16 f2bf(float v) { return __float2bfloat16(v); }

__device__ __forceinline__ uint4 pack8bf(float4 a, float4 b) {
    __align__(16) bf16 t[8];
    t[0] = f2bf(a.x); t[1] = f2bf(a.y); t[2] = f2bf(a.z); t[3] = f2bf(a.w);
    t[4] = f2bf(b.x); t[5] = f2bf(b.y); t[6] = f2bf(b.z); t[7] = f2bf(b.w);
    return *(const uint4*)t;
}

#define RSTR 80

// ------------------------------------------------------------ GEMM body (64-tile)
// EPI: 0 = fp32 out, 1 = fp32 + residual, 2 = relu->bf16, 3 = bf16
template <int EPI>
__device__ __forceinline__ void gemm64_body(char* lds,
        const bf16* __restrict__ A, const bf16* __restrict__ Bt,
        void* __restrict__ Cv, const float* __restrict__ R,
        int M, int N, int K, int bx, int by, int kbeg, int kend) {
    char* As = lds;
    char* Bs = lds + 2 * 64 * RSTR;
    const int tid = threadIdx.x;
    const int bm = bx * 64, bn = by * 64;
    const int w = tid >> 6, lane = tid & 63;
    const int wr = (w >> 1) * 32, wc = (w & 1) * 32;
    const int m0 = lane & 15, q4 = lane >> 4;

    f32x4 acc[2][2] = {};

    const int rA = tid >> 3;
    const int cA = tid & 7;
    const int ksP = cA >> 2;
    const int cB = (cA & 3) * 16;
    const int cE = cA * 8;

    for (int k0 = kbeg; k0 < kend; k0 += 64) {
        uint4 a0 = *(const uint4*)(A  + (size_t)(bm + rA) * K + k0 + cE);
        uint4 a1 = *(const uint4*)(A  + (size_t)(bm + rA + 32) * K + k0 + cE);
        uint4 b0 = *(const uint4*)(Bt + (size_t)(bn + rA) * K + k0 + cE);
        uint4 b1 = *(const uint4*)(Bt + (size_t)(bn + rA + 32) * K + k0 + cE);
        __syncthreads();
        *(uint4*)(As + ksP * (64 * RSTR) + rA * RSTR + cB) = a0;
        *(uint4*)(As + ksP * (64 * RSTR) + (rA + 32) * RSTR + cB) = a1;
        *(uint4*)(Bs + ksP * (64 * RSTR) + rA * RSTR + cB) = b0;
        *(uint4*)(Bs + ksP * (64 * RSTR) + (rA + 32) * RSTR + cB) = b1;
        __syncthreads();
        short8 af[2][2], bfr[2][2];
        #pragma unroll
        for (int ks = 0; ks < 2; ++ks)
            #pragma unroll
            for (int t = 0; t < 2; ++t) {
                af[ks][t]  = *(const short8*)(As + ks * (64 * RSTR) + (wr + t * 16 + m0) * RSTR + q4 * 16);
                bfr[ks][t] = *(const short8*)(Bs + ks * (64 * RSTR) + (wc + t * 16 + m0) * RSTR + q4 * 16);
            }
        #pragma unroll
        for (int ks = 0; ks < 2; ++ks)
            #pragma unroll
            for (int mt = 0; mt < 2; ++mt)
                #pragma unroll
                for (int nt = 0; nt < 2; ++nt)
                    acc[mt][nt] = __builtin_amdgcn_mfma_f32_16x16x32_bf16(
                        af[ks][mt], bfr[ks][nt], acc[mt][nt], 0, 0, 0);
    }

    if (EPI <= 1) {
        float* C = (float*)Cv;
        #pragma unroll
        for (int mt = 0; mt < 2; ++mt)
            #pragma unroll
            for (int i = 0; i < 4; ++i) {
                int row = bm + wr + mt * 16 + q4 * 4 + i;
                #pragma unroll
                for (int nt = 0; nt < 2; ++nt) {
                    int col = bn + wc + nt * 16 + m0;
                    float v = acc[mt][nt][i];
                    if (EPI == 1) v += R[(size_t)row * N + col];
                    C[(size_t)row * N + col] = v;
                }
            }
    } else {
        bf16* C = (bf16*)Cv;
        #pragma unroll
        for (int mt = 0; mt < 2; ++mt)
            #pragma unroll
            for (int i = 0; i < 4; ++i) {
                int row = bm + wr + mt * 16 + q4 * 4 + i;
                #pragma unroll
                for (int nt = 0; nt < 2; ++nt) {
                    int col = bn + wc + nt * 16 + m0;
                    float v = acc[mt][nt][i];
                    if (EPI == 2) v = fmaxf(v, 0.0f);
                    C[(size_t)row * N + col] = __float2bfloat16(v);
                }
            }
    }
}

template <int EPI, bool SPLIT>
__launch_bounds__(256)
__global__ void mfma_gemm_s(const bf16* __restrict__ A, const bf16* __restrict__ Bt,
                            void* __restrict__ Cv, const float* __restrict__ R,
                            int M, int N, int K) {
    __shared__ __align__(16) char lds[4 * 64 * RSTR];
    int kbeg = 0, kend = K;
    const bf16* B2 = Bt;
    void* C2 = Cv;
    if (SPLIT) {
        int ks = K / gridDim.z;
        kbeg = blockIdx.z * ks;
        kend = kbeg + ks;
        C2 = (void*)((float*)Cv + (size_t)blockIdx.z * M * N);
        gemm64_body<0>(lds, A, B2, C2, nullptr, M, N, K, blockIdx.x, blockIdx.y, kbeg, kend);
    } else {
        B2 = Bt + (size_t)blockIdx.z * N * K;
        if (EPI <= 1) C2 = (void*)((float*)Cv + (size_t)blockIdx.z * M * N);
        gemm64_body<EPI>(lds, A, B2, C2, R, M, N, K, blockIdx.x, blockIdx.y, kbeg, kend);
    }
}

// ------------------------------------------------ device bodies (shared pieces)

// per-(b,h) q . basis^T : P[(b,h,i,r)] = sum_{d<64} q[b,i,h*64+d] * Bz[r,h*64+d]
__device__ __forceinline__ void ptable_body(char* lds, const float* __restrict__ q,
        const bf16* __restrict__ Bt, float* __restrict__ P, int b, int h, bool shr) {
    char* As = lds;
    char* Bs = lds + 2 * 64 * RSTR;
    const int tid = threadIdx.x;
    const int w = tid >> 6, lane = tid & 63;
    const int wr = (w >> 1) * 32, wc = (w & 1) * 32;
    const int m0 = lane & 15, q4 = lane >> 4;
    const int rA = tid >> 3;
    const int cA = tid & 7;
    const int ksP = cA >> 2;
    const int cB = (cA & 3) * 16;
    const int cE = cA * 8;

    const float* Aq = q + (size_t)(b * 64) * 512 + h * 64;
    const bf16*  Bb = Bt + (shr ? (size_t)0 : (size_t)b * 64 * 512) + h * 64;

    float4 fa0 = *(const float4*)(Aq + (size_t)rA * 512 + cE);
    float4 fa1 = *(const float4*)(Aq + (size_t)rA * 512 + cE + 4);
    float4 fb0 = *(const float4*)(Aq + (size_t)(rA + 32) * 512 + cE);
    float4 fb1 = *(const float4*)(Aq + (size_t)(rA + 32) * 512 + cE + 4);
    uint4 bv0 = *(const uint4*)(Bb + (size_t)rA * 512 + cE);
    uint4 bv1 = *(const uint4*)(Bb + (size_t)(rA + 32) * 512 + cE);
    uint4 av0 = pack8bf(fa0, fa1);
    uint4 av1 = pack8bf(fb0, fb1);
    *(uint4*)(As + ksP * (64 * RSTR) + rA * RSTR + cB) = av0;
    *(uint4*)(As + ksP * (64 * RSTR) + (rA + 32) * RSTR + cB) = av1;
    *(uint4*)(Bs + ksP * (64 * RSTR) + rA * RSTR + cB) = bv0;
    *(uint4*)(Bs + ksP * (64 * RSTR) + (rA + 32) * RSTR + cB) = bv1;
    __syncthreads();

    f32x4 acc[2][2] = {};
    short8 af[2][2], bfr[2][2];
    #pragma unroll
    for (int ks = 0; ks < 2; ++ks)
        #pragma unroll
        for (int t = 0; t < 2; ++t) {
            af[ks][t]  = *(const short8*)(As + ks * (64 * RSTR) + (wr + t * 16 + m0) * RSTR + q4 * 16);
            bfr[ks][t] = *(const short8*)(Bs + ks * (64 * RSTR) + (wc + t * 16 + m0) * RSTR + q4 * 16);
        }
    #pragma unroll
    for (int ks = 0; ks < 2; ++ks)
        #pragma unroll
        for (int mt = 0; mt < 2; ++mt)
            #pragma unroll
            for (int nt = 0; nt < 2; ++nt)
                acc[mt][nt] = __builtin_amdgcn_mfma_f32_16x16x32_bf16(
                    af[ks][mt], bfr[ks][nt], acc[mt][nt], 0, 0, 0);

    #pragma unroll
    for (int mt = 0; mt < 2; ++mt)
        #pragma unroll
        for (int i = 0; i < 4; ++i) {
            int row = wr + mt * 16 + q4 * 4 + i;
            #pragma unroll
            for (int nt = 0; nt < 2; ++nt) {
                int col = wc + nt * 16 + m0;
                P[(((size_t)b * 8 + h) * 64 + row) * 64 + col] = acc[mt][nt][i];
            }
        }
}

// u_bf[b,i,h,k] = sum_d q[b,i,h*64+d] * Wew3[k,h*64+d]
__device__ __forceinline__ void ugemm_body(char* lds, const float* __restrict__ q,
        const bf16* __restrict__ wc3, bf16* __restrict__ ubf, int h, int mb, int nb) {
    char* As = lds;
    char* Bs = lds + 2 * 64 * RSTR;
    const int tid = threadIdx.x;
    const int w = tid >> 6, lane = tid & 63;
    const int wr = (w >> 1) * 32, wc = (w & 1) * 32;
    const int m0 = lane & 15, q4 = lane >> 4;
    const int rA = tid >> 3;
    const int cA = tid & 7;
    const int ksP = cA >> 2;
    const int cB = (cA & 3) * 16;
    const int cE = cA * 8;

    const float* Aq = q + (size_t)(mb * 64) * 512 + h * 64;
    const bf16*  Bt = wc3 + (size_t)(nb * 64) * 512 + h * 64;

    float4 fa0 = *(const float4*)(Aq + (size_t)rA * 512 + cE);
    float4 fa1 = *(const float4*)(Aq + (size_t)rA * 512 + cE + 4);
    float4 fb0 = *(const float4*)(Aq + (size_t)(rA + 32) * 512 + cE);
    float4 fb1 = *(const float4*)(Aq + (size_t)(rA + 32) * 512 + cE + 4);
    uint4 b0 = *(const uint4*)(Bt + (size_t)rA * 512 + cE);
    uint4 b1 = *(const uint4*)(Bt + (size_t)(rA + 32) * 512 + cE);
    uint4 a0 = pack8bf(fa0, fa1);
    uint4 a1 = pack8bf(fb0, fb1);
    *(uint4*)(As + ksP * (64 * RSTR) + rA * RSTR + cB) = a0;
    *(uint4*)(As + ksP * (64 * RSTR) + (rA + 32) * RSTR + cB) = a1;
    *(uint4*)(Bs + ksP * (64 * RSTR) + rA * RSTR + cB) = b0;
    *(uint4*)(Bs + ksP * (64 * RSTR) + (rA + 32) * RSTR + cB) = b1;
    __syncthreads();

    f32x4 acc[2][2] = {};
    short8 af[2][2], bfr[2][2];
    #pragma unroll
    for (int ks = 0; ks < 2; ++ks)
        #pragma unroll
        for (int t = 0; t < 2; ++t) {
            af[ks][t]  = *(const short8*)(As + ks * (64 * RSTR) + (wr + t * 16 + m0) * RSTR + q4 * 16);
            bfr[ks][t] = *(const short8*)(Bs + ks * (64 * RSTR) + (wc + t * 16 + m0) * RSTR + q4 * 16);
        }
    #pragma unroll
    for (int ks = 0; ks < 2; ++ks)
        #pragma unroll
        for (int mt = 0; mt < 2; ++mt)
            #pragma unroll
            for (int nt = 0; nt < 2; ++nt)
                acc[mt][nt] = __builtin_amdgcn_mfma_f32_16x16x32_bf16(
                    af[ks][mt], bfr[ks][nt], acc[mt][nt], 0, 0, 0);

    #pragma unroll
    for (int mt = 0; mt < 2; ++mt)
        #pragma unroll
        for (int i = 0; i < 4; ++i) {
            int row = mb * 64 + wr + mt * 16 + q4 * 4 + i;
            #pragma unroll
            for (int nt = 0; nt < 2; ++nt) {
                int col = nb * 64 + wc + nt * 16 + m0;
                ubf[(size_t)row * 4096 + h * 512 + col] = f2bf(acc[mt][nt][i]);
            }
        }
}

// edge softmax coeffs for l=0 from Gram tables (G0 in gbuf slot 5, TEE in slot 6)
__device__ __forceinline__ void coeff0_body(const int* __restrict__ adj,
        const float* __restrict__ gbuf, int row, int j,
        float* __restrict__ w0o, float* __restrict__ w1o, float* __restrict__ w2o) {
    int b = row >> 6, i = row & 63;
    int p = row * 64 + j;
    int t = adj[p];
    const float* G0  = gbuf + 5 * 32768 + (size_t)b * 4096;
    const float* TEE = gbuf + 6 * 32768;
    float s0 = TEE[t * 64 + t];
    float s1 = G0[t * 64 + i];
    float s2 = G0[t * 64 + j];
    float t0 = s0 * INV_SCALE, t1 = s1 * INV_SCALE, t2 = s2 * INV_SCALE;
    float m = fmaxf(t0, fmaxf(t1, t2));
    float e0 = expf(t0 - m), e1 = expf(t1 - m), e2 = expf(t2 - m);
    float inv = 1.0f / (e0 + e1 + e2);
    w0o[p] = e0 * inv;
    w1o[p] = e1 * inv;
    w2o[p] = e2 * inv;
}

// edge softmax coeffs from l=1 Gram tables (per-thread; row=(b,i), j)
__device__ __forceinline__ void coeff1_body(const int* __restrict__ adj,
        const float* __restrict__ c0a, const float* __restrict__ c1a, const float* __restrict__ c2a,
        const float* __restrict__ gbuf, int row, int j,
        float* __restrict__ w0o, float* __restrict__ w1o, float* __restrict__ w2o) {
    int b = row >> 6, i = row & 63;
    int p = row * 64 + j;
    int t = adj[p];
    const float* TXX = gbuf + 0 * 32768 + (size_t)b * 4096;
    const float* TEX = gbuf + 1 * 32768 + (size_t)b * 4096;
    const float* TXx = gbuf + 2 * 32768 + (size_t)b * 4096;
    const float* TEx = gbuf + 3 * 32768 + (size_t)b * 4096;
    const float* TEE = gbuf + 4 * 32768 + (size_t)b * 4096;
    float c0 = c0a[p], c1 = c1a[p], c2 = c2a[p];
    float s1 = c0 * TEx[t * 64 + i] + c1 * TXx[i * 64 + i] + c2 * TXx[j * 64 + i];
    float s2 = c0 * TEx[t * 64 + j] + c1 * TXx[i * 64 + j] + c2 * TXx[j * 64 + j];
    float s0 = c0 * c0 * TEE[t * 64 + t] + c1 * c1 * TXX[i * 64 + i] + c2 * c2 * TXX[j * 64 + j]
             + 2.f * c0 * c1 * TEX[t * 64 + i] + 2.f * c0 * c2 * TEX[t * 64 + j]
             + 2.f * c1 * c2 * TXX[i * 64 + j];
    float t0 = s0 * INV_SCALE, t1 = s1 * INV_SCALE, t2 = s2 * INV_SCALE;
    float m = fmaxf(t0, fmaxf(t1, t2));
    float e0 = expf(t0 - m), e1 = expf(t1 - m), e2 = expf(t2 - m);
    float inv = 1.0f / (e0 + e1 + e2);
    w0o[p] = e0 * inv;
    w1o[p] = e1 * inv;
    w2o[p] = e2 * inv;
}

// edge softmax coeffs from l=2 Gram tables
__device__ __forceinline__ void coeff2_body(const int* __restrict__ adj,
        const float* __restrict__ c0a, const float* __restrict__ c1a, const float* __restrict__ c2a,
        const float* __restrict__ c0b, const float* __restrict__ c1b, const float* __restrict__ c2b,
        const float* __restrict__ gbuf, int row, int j,
        float* __restrict__ w0o, float* __restrict__ w1o, float* __restrict__ w2o) {
    int b = row >> 6, i = row & 63;
    int p = row * 64 + j;
    int t = adj[p];
    const float* TXX = gbuf + 0 * 32768 + (size_t)b * 4096;
    const float* TXY = gbuf + 1 * 32768 + (size_t)b * 4096;
    const float* TYY = gbuf + 2 * 32768 + (size_t)b * 4096;
    const float* TEX = gbuf + 3 * 32768 + (size_t)b * 4096;
    const float* TEY = gbuf + 4 * 32768 + (size_t)b * 4096;
    const float* TEE = gbuf + 5 * 32768 + (size_t)b * 4096;
    const float* TXx = gbuf + 6 * 32768 + (size_t)b * 4096;
    const float* TYx = gbuf + 7 * 32768 + (size_t)b * 4096;
    const float* TEx = gbuf + 8 * 32768 + (size_t)b * 4096;
    float a0 = c0b[p];
    float AE = a0 * c0a[p], Aa = a0 * c1a[p], Ab = a0 * c2a[p];
    float Ac = c1b[p], Ad = c2b[p];
    float s1 = AE * TEx[t * 64 + i] + Aa * TXx[i * 64 + i] + Ab * TXx[j * 64 + i]
             + Ac * TYx[i * 64 + i] + Ad * TYx[j * 64 + i];
    float s2 = AE * TEx[t * 64 + j] + Aa * TXx[i * 64 + j] + Ab * TXx[j * 64 + j]
             + Ac * TYx[i * 64 + j] + Ad * TYx[j * 64 + j];
    float s0 = AE * AE * TEE[t * 64 + t] + Aa * Aa * TXX[i * 64 + i] + Ab * Ab * TXX[j * 64 + j]
             + Ac * Ac * TYY[i * 64 + i] + Ad * Ad * TYY[j * 64 + j]
             + 2.f * AE * Aa * TEX[t * 64 + i] + 2.f * AE * Ab * TEX[t * 64 + j]
             + 2.f * AE * Ac * TEY[t * 64 + i] + 2.f * AE * Ad * TEY[t * 64 + j]
             + 2.f * Aa * Ab * TXX[i * 64 + j]
             + 2.f * Aa * Ac * TXY[i * 64 + i] + 2.f * Aa * Ad * TXY[i * 64 + j]
             + 2.f * Ab * Ac * TXY[j * 64 + i] + 2.f * Ab * Ad * TXY[j * 64 + j]
             + 2.f * Ac * Ad * TYY[i * 64 + j];
    float t0 = s0 * INV_SCALE, t1 = s1 * INV_SCALE, t2 = s2 * INV_SCALE;
    float m = fmaxf(t0, fmaxf(t1, t2));
    float e0 = expf(t0 - m), e1 = expf(t1 - m), e2 = expf(t2 - m);
    float inv = 1.0f / (e0 + e1 + e2);
    w0o[p] = e0 * inv;
    w1o[p] = e1 * inv;
    w2o[p] = e2 * inv;
}

// ------------------------------------------------ merged one-shot setup kernel
// grid: [0,512) embed | [512,1152) sq transpose (2x 64x64 tiles/block)
//       [1152,2176) rect transpose (2x tiles/block) | [2176,2304) bond_bf | [2304,2432) cast_w3
__launch_bounds__(256)
__global__ void setup_kernel(const int* __restrict__ ids, const float* __restrict__ atom_emb,
                             const float* __restrict__ bond_emb,
                             const float* __restrict__ Wq, const float* __restrict__ Wk,
                             const float* __restrict__ Wv, const float* __restrict__ Wew,
                             const float* __restrict__ Wst,
                             const float* __restrict__ Wf1, const float* __restrict__ Wf2,
                             float* __restrict__ xn, bf16* __restrict__ xn_bf,
                             bf16* __restrict__ qkvt, bf16* __restrict__ ewt,
                             bf16* __restrict__ stackt,
                             bf16* __restrict__ f1t, bf16* __restrict__ f2t,
                             bf16* __restrict__ bond_bf, bf16* __restrict__ wc3) {
    __shared__ __align__(16) float smem[64 * 65];   // 16.6 KB; reused by all sections
    const size_t KN = (size_t)H_ * H_;
    int bid = blockIdx.x;
    int tid = threadIdx.x;

    if (bid < 512) {
        // ---- embed + LN
        int row = bid;
        const float* r = atom_emb + (size_t)ids[row] * H_;
        float x0 = r[tid], x1 = r[tid + 256];
        float s = x0 + x1, sq = x0 * x0 + x1 * x1;
        #pragma unroll
        for (int off = 32; off; off >>= 1) {
            s  += __shfl_xor(s,  off);
            sq += __shfl_xor(sq, off);
        }
        int w = tid >> 6;
        if ((tid & 63) == 0) { smem[w] = s; smem[4 + w] = sq; }
        __syncthreads();
        float S = smem[0] + smem[1] + smem[2] + smem[3];
        float Q = smem[4] + smem[5] + smem[6] + smem[7];
        float mean = S * (1.0f / H_);
        float var  = Q * (1.0f / H_) - mean * mean;
        float inv  = rsqrtf(var + 1e-5f);
        float y0 = (x0 - mean) * inv, y1 = (x1 - mean) * inv;
        xn[(size_t)row * H_ + tid]       = y0;
        xn[(size_t)row * H_ + tid + 256] = y1;
        xn_bf[(size_t)row * H_ + tid]       = f2bf(y0);
        xn_bf[(size_t)row * H_ + tid + 256] = f2bf(y1);
    } else if (bid < 2176) {
        // ---- 64x64 fp32 -> bf16 transpose tiles, 2 tiles per block
        for (int sub = 0; sub < 2; ++sub) {
            const float* W; bf16* Wt; int K, N, kb, nb;
            if (bid < 1152) {
                int idx = (bid - 512) * 2 + sub;     // [0,1280)
                int z = idx >> 6, rem = idx & 63;
                kb = rem & 7; nb = rem >> 3;
                K = 512; N = 512;
                if (z < 12) {
                    int sss = z >> 2, l = z & 3;
                    W  = (sss == 0 ? Wq : sss == 1 ? Wk : Wv) + (size_t)l * KN;
                    Wt = qkvt + (size_t)l * 3 * KN + (size_t)sss * KN;
                } else if (z < 16) {
                    int l = z - 12;
                    W = Wew + (size_t)l * KN; Wt = ewt + (size_t)l * KN;
                } else {
                    int l = z - 16;
                    W = Wst + (size_t)l * KN; Wt = stackt + (size_t)l * KN;
                }
            } else {
                int idx = (bid - 1152) * 2 + sub;    // [0,2048)
                int z = idx >> 8;                    // 0..7
                int idx2 = idx & 255;
                const size_t KN4 = (size_t)4 * H_ * H_;
                if (z < 4) {
                    W = Wf1 + (size_t)z * KN4; Wt = f1t + (size_t)z * KN4; K = 512; N = 2048;
                    kb = idx2 & 7; nb = idx2 >> 3;
                } else {
                    W = Wf2 + (size_t)(z - 4) * KN4; Wt = f2t + (size_t)(z - 4) * KN4; K = 2048; N = 512;
                    kb = idx2 >> 3; nb = idx2 & 7;
                }
            }
            int k0 = kb * 64, n0 = nb * 64;
            float (*tt)[65] = (float(*)[65])smem;
            int rr = tid >> 4, c4 = (tid & 15) * 4;
            if (sub) __syncthreads();   // protect smem reuse between tiles
            #pragma unroll
            for (int it = 0; it < 4; ++it) {
                float4 v = *(const float4*)(W + (size_t)(k0 + rr + it * 16) * N + n0 + c4);
                tt[rr + it * 16][c4 + 0] = v.x;
                tt[rr + it * 16][c4 + 1] = v.y;
                tt[rr + it * 16][c4 + 2] = v.z;
                tt[rr + it * 16][c4 + 3] = v.w;
            }
            __syncthreads();
            int nr = tid >> 3, k8 = (tid & 7) * 8;
            #pragma unroll
            for (int it = 0; it < 2; ++it) {
                int nn = nr + it * 32;
                __align__(16) bf16 ob[8];
                #pragma unroll
                for (int e = 0; e < 8; ++e)
                    ob[e] = f2bf(tt[k8 + e][nn]);
                *(uint4*)(Wt + (size_t)(n0 + nn) * K + k0 + k8) = *(const uint4*)ob;
            }
        }
    } else if (bid < 2304) {
        // ---- bond_bf: bf16 cast of bond_emb rows <8; rows 8..63 zero (pad for E0 GEMM)
        int idx = bid - 2176;
        int t = idx >> 1;
        int c = (idx & 1) * 256 + tid;
        bond_bf[t * 512 + c] = (t < 8) ? f2bf(bond_emb[t * 512 + c]) : f2bf(0.0f);
    } else {
        // ---- cast Wew3 -> bf16
        int idx = bid - 2304;
        int gid = idx * 256 + tid;
        const float4* p = (const float4*)(Wew + 3 * KN + (size_t)gid * 8);
        float4 a = p[0], b = p[1];
        *(uint4*)(wc3 + (size_t)gid * 8) = pack8bf(a, b);
    }
}

// ------------------------------------------------ l=0 head: qkv + E0 MFMA GEMM
// grid: [0,192) qkv (z=bid>>6, mb=(bid>>3)&7, by=bid&7) | [192,200) E0 = bond_bf @ ewt0
__launch_bounds__(256)
__global__ void qkv0_e0(const bf16* __restrict__ xn_bf, const bf16* __restrict__ qkvt,
                        float* __restrict__ qkv,
                        const bf16* __restrict__ bond_bf, const bf16* __restrict__ ewt0,
                        bf16* __restrict__ E0) {
    __shared__ __align__(16) char lds[4 * 64 * RSTR];
    int bid = blockIdx.x;
    if (bid < 192) {
        int z = bid >> 6, rem = bid & 63;
        int mb = rem >> 3, by = rem & 7;
        gemm64_body<0>(lds, xn_bf, qkvt + (size_t)z * 262144,
                       qkv + (size_t)z * 262144, nullptr, 512, 512, 512, mb, by, 0, 512);
    } else {
        gemm64_body<3>(lds, bond_bf, ewt0, E0, nullptr, 64, 512, 512,
                       0, bid - 192, 0, 512);
    }
}

// ------------------------------------------------ l=1 head: basis1 + qkv + l=0 Gram tables
// grid: [0,264) gemm (bx=bid>>3, by=bid&7) | [264,272) G0_b = E0 @ x_b^T | [272] TEE = E0 @ E0^T
__launch_bounds__(256)
__global__ void basis1_qkv_g0(const bf16* __restrict__ x_bf, const bf16* __restrict__ E0,
                              const bf16* __restrict__ ewt1,
                              bf16* __restrict__ xw1, bf16* __restrict__ e0w1,
                              const bf16* __restrict__ xn_bf, const bf16* __restrict__ qkvt_l,
                              float* __restrict__ qkv, float* __restrict__ gbuf) {
    __shared__ __align__(16) char lds[4 * 64 * RSTR];
    int bid = blockIdx.x;
    if (bid < 264) {
        int bx = bid >> 3, by = bid & 7;
        if (bx < 8)
            gemm64_body<3>(lds, x_bf, ewt1, xw1, nullptr, 512, 512, 512, bx, by, 0, 512);
        else if (bx == 8)
            gemm64_body<3>(lds, E0, ewt1, e0w1, nullptr, 64, 512, 512, 0, by, 0, 512);
        else {
            int tq = bx - 9;
            int z = tq >> 3, mb = tq & 7;
            gemm64_body<0>(lds, xn_bf, qkvt_l + (size_t)z * 262144,
                           qkv + (size_t)z * 262144, nullptr, 512, 512, 512, mb, by, 0, 512);
        }
    } else if (bid < 272) {
        int b = bid - 264;
        gemm64_body<0>(lds, E0, x_bf + (size_t)b * 32768,
                       gbuf + 5 * 32768 + (size_t)b * 4096, nullptr,
                       64, 64, 512, 0, 0, 0, 512);
    } else {
        gemm64_body<0>(lds, E0, E0, gbuf + 6 * 32768, nullptr,
                       64, 64, 512, 0, 0, 0, 512);
    }
}

// ------------------------------------------------ l=1: ptable (2 bases) + coeff0 assemble
// grid: [0,128) ptable (z=bid>>6, b=(bid&63)>>3, h=bid&7) | [128,192) coeff0 (8 rows each)
__launch_bounds__(256)
__global__ void ptable1c(const float* __restrict__ q,
                         const bf16* __restrict__ B0, const bf16* __restrict__ B1,
                         float* __restrict__ P0, float* __restrict__ P1,
                         const int* __restrict__ adj, const float* __restrict__ gbuf,
                         float* __restrict__ w0o, float* __restrict__ w1o,
                         float* __restrict__ w2o) {
    __shared__ __align__(16) char lds[4 * 64 * RSTR];
    int bid = blockIdx.x;
    if (bid < 128) {
        int z = bid >> 6, rem = bid & 63;
        int b = rem >> 3, h = rem & 7;
        const bf16* Bt = (z == 0) ? B0 : B1;
        float* P = (z == 0) ? P0 : P1;
        ptable_body(lds, q, Bt, P, b, h, z == 1);
    } else {
        int k = bid - 128;
        int tid = threadIdx.x;
        int j = tid & 63;
        #pragma unroll
        for (int pass = 0; pass < 2; ++pass) {
            int row = k * 8 + pass * 4 + (tid >> 6);
            coeff0_body(adj, gbuf, row, j, w0o, w1o, w2o);
        }
    }
}

// ------------------------------------------------ l=2 head: basis2 + qkv + gram1
// grid: [0,328) gemm | [328,368) gram1 (b=k&7, z=k>>3)
__launch_bounds__(256)
__global__ void basis2_qkv_g1(const bf16* __restrict__ xw1, const bf16* __restrict__ x_bf,
                              const bf16* __restrict__ e0w1, const bf16* __restrict__ ewt2,
                              bf16* __restrict__ xw12, bf16* __restrict__ x2w2,
                              bf16* __restrict__ e0w12,
                              const bf16* __restrict__ xn_bf, const bf16* __restrict__ qkvt_l,
                              float* __restrict__ qkv, float* __restrict__ gbuf) {
    __shared__ __align__(16) char lds[4 * 64 * RSTR];
    int bid = blockIdx.x;
    if (bid < 328) {
        int bx = bid >> 3, by = bid & 7;
        if (bx < 8)
            gemm64_body<3>(lds, xw1, ewt2, xw12, nullptr, 512, 512, 512, bx, by, 0, 512);
        else if (bx < 16)
            gemm64_body<3>(lds, x_bf, ewt2, x2w2, nullptr, 512, 512, 512, bx - 8, by, 0, 512);
        else if (bx == 16)
            gemm64_body<3>(lds, e0w1, ewt2, e0w12, nullptr, 64, 512, 512, 0, by, 0, 512);
        else {
            int tq = bx - 17;
            int z = tq >> 3, mb = tq & 7;
            gemm64_body<0>(lds, xn_bf, qkvt_l + (size_t)z * 262144,
                           qkv + (size_t)z * 262144, nullptr, 512, 512, 512, mb, by, 0, 512);
        }
    } else {
        int k = bid - 328;
        int b = k & 7, z = k >> 3;
        size_t ob = (size_t)b * 32768;
        const bf16 *A, *Bt;
        switch (z) {
            case 0: A = xw1 + ob; Bt = xw1 + ob; break;
            case 1: A = e0w1;     Bt = xw1 + ob; break;
            case 2: A = xw1 + ob; Bt = x_bf + ob; break;
            case 3: A = e0w1;     Bt = x_bf + ob; break;
            default: A = e0w1;    Bt = e0w1;     break;
        }
        float* C = gbuf + (size_t)z * 32768 + (size_t)b * 4096;
        gemm64_body<0>(lds, A, Bt, C, nullptr, 64, 64, 512, 0, 0, 0, 512);
    }
}

// ------------------------------------------------ l=2: ptable(3) + coeff1
// grid: [0,192) ptable (z=bid>>6, b=(bid&63)>>3, h=bid&7) | [192,256) coeff1 (8 rows each)
__launch_bounds__(256)
__global__ void ptable2c(const float* __restrict__ q,
                         const bf16* __restrict__ B0, const bf16* __restrict__ B1,
                         const bf16* __restrict__ B2,
                         float* __restrict__ P0, float* __restrict__ P1,
                         float* __restrict__ P2,
                         const int* __restrict__ adj,
                         const float* __restrict__ c0a, const float* __restrict__ c1a,
                         const float* __restrict__ c2a, const float* __restrict__ gbuf,
                         float* __restrict__ w0o, float* __restrict__ w1o,
                         float* __restrict__ w2o) {
    __shared__ __align__(16) char lds[4 * 64 * RSTR];
    int bid = blockIdx.x;
    if (bid < 192) {
        int z = bid >> 6, rem = bid & 63;
        int b = rem >> 3, h = rem & 7;
        const bf16* Bt = (z == 0) ? B0 : (z == 1 ? B1 : B2);
        float* P = (z == 0) ? P0 : (z == 1 ? P1 : P2);
        ptable_body(lds, q, Bt, P, b, h, z == 2);
    } else {
        int k = bid - 192;
        int tid = threadIdx.x;
        int j = tid & 63;
        #pragma unroll
        for (int pass = 0; pass < 2; ++pass) {
            int row = k * 8 + pass * 4 + (tid >> 6);
            coeff1_body(adj, c0a, c1a, c2a, gbuf, row, j, w0o, w1o, w2o);
        }
    }
}

// ------------------------------------------------ l=3 head: qkv + gram2
// grid: [0,192) qkv (z=bid>>6, mb=(bid>>3)&7, by=bid&7) | [192,264) gram2
__launch_bounds__(256)
__global__ void l3qkv_g2(const bf16* __restrict__ xn_bf, const bf16* __restrict__ qkvt_l,
                         float* __restrict__ qkv,
                         const bf16* __restrict__ xw12, const bf16* __restrict__ x2w2,
                         const bf16* __restrict__ e0w12, const bf16* __restrict__ x_bf,
                         float* __restrict__ gbuf) {
    __shared__ __align__(16) char lds[4 * 64 * RSTR];
    int bid = blockIdx.x;
    if (bid < 192) {
        int z = bid >> 6, rem = bid & 63;
        int mb = rem >> 3, by = rem & 7;
        gemm64_body<0>(lds, xn_bf, qkvt_l + (size_t)z * 262144,
                       qkv + (size_t)z * 262144, nullptr, 512, 512, 512, mb, by, 0, 512);
    } else {
        int k = bid - 192;
        int b = k & 7, z = k >> 3;
        size_t ob = (size_t)b * 32768;
        const bf16 *A, *Bt;
        switch (z) {
            case 0: A = xw12 + ob; Bt = xw12 + ob; break;
            case 1: A = xw12 + ob; Bt = x2w2 + ob; break;
            case 2: A = x2w2 + ob; Bt = x2w2 + ob; break;
            case 3: A = e0w12;     Bt = xw12 + ob; break;
            case 4: A = e0w12;     Bt = x2w2 + ob; break;
            case 5: A = e0w12;     Bt = e0w12;     break;
            case 6: A = xw12 + ob; Bt = x_bf + ob; break;
            case 7: A = x2w2 + ob; Bt = x_bf + ob; break;
            default: A = e0w12;    Bt = x_bf + ob; break;
        }
        float* C = gbuf + (size_t)z * 32768 + (size_t)b * 4096;
        gemm64_body<0>(lds, A, Bt, C, nullptr, 64, 64, 512, 0, 0, 0, 512);
    }
}

// ------------------------------------------------ l=3: u_gemm + coeff2
// grid: [0,512) u (h=bid>>6, mb=(bid>>3)&7, nb=bid&7) | [512,576) coeff2 (8 rows each)
__launch_bounds__(256)
__global__ void u_c2(const float* __restrict__ q, const bf16* __restrict__ wc3,
                     bf16* __restrict__ ubf,
                     const int* __restrict__ adj,
                     const float* __restrict__ c0a, const float* __restrict__ c1a,
                     const float* __restrict__ c2a,
                     const float* __restrict__ c0b, const float* __restrict__ c1b,
                     const float* __restrict__ c2b,
                     const float* __restrict__ gbuf,
                     float* __restrict__ w0o, float* __restrict__ w1o,
                     float* __restrict__ w2o) {
    __shared__ __align__(16) char lds[4 * 64 * RSTR];
    int bid = blockIdx.x;
    if (bid < 512) {
        int h = bid >> 6, mb = (bid >> 3) & 7, nb = bid & 7;
        ugemm_body(lds, q, wc3, ubf, h, mb, nb);
    } else {
        int k = bid - 512;
        int tid = threadIdx.x;
        int j = tid & 63;
        #pragma unroll
        for (int pass = 0; pass < 2; ++pass) {
            int row = k * 8 + pass * 4 + (tid >> 6);
            coeff2_body(adj, c0a, c1a, c2a, c0b, c1b, c2b, gbuf, row, j, w0o, w1o, w2o);
        }
    }
}

// M-tables: for each b, U_b (512 rows (i,h) x 512 k) @ basis_b^T (64 x 512)
__launch_bounds__(256)
__global__ void mbuf_gemm(const bf16* __restrict__ ubf, const bf16* __restrict__ xw12,
                          const bf16* __restrict__ x2w2, const bf16* __restrict__ x_bf,
                          const bf16* __restrict__ e0w12,
                          float* __restrict__ MX, float* __restrict__ MY,
                          float* __restrict__ MZ, float* __restrict__ DE) {
    __shared__ __align__(16) char lds[4 * 64 * RSTR];
    int b = blockIdx.x, mt = blockIdx.y, z = blockIdx.z;
    const bf16* A = ubf + (size_t)b * 512 * 512;
    const bf16* Bt;
    float* C;
    if (z == 0)      { Bt = xw12 + (size_t)b * 64 * 512; C = MX + (size_t)b * 512 * 64; }
    else if (z == 1) { Bt = x2w2 + (size_t)b * 64 * 512; C = MY + (size_t)b * 512 * 64; }
    else if (z == 2) { Bt = x_bf + (size_t)b * 64 * 512; C = MZ + (size_t)b * 512 * 64; }
    else             { Bt = e0w12;                        C = DE + (size_t)b * 512 * 64; }
    gemm64_body<0>(lds, A, Bt, C, nullptr, 512, 64, 512, mt, 0, 0, 512);
}

// ---------------------- split-K reduce + residual + LN variants
__global__ void reduce_stack_ln(const float* __restrict__ part, const float* __restrict__ base,
                                float* __restrict__ resid, bf16* __restrict__ ffin_bf) {
    const int MN = 512 * H_;
    int row = blockIdx.x;
    int tid = threadIdx.x;
    size_t b0 = (size_t)row * H_;
    float v0 = base[b0 + tid], v1 = base[b0 + tid + 256];
    #pragma unroll
    for (int s = 0; s < 4; ++s) {
        v0 += part[(size_t)s * MN + b0 + tid];
        v1 += part[(size_t)s * MN + b0 + tid + 256];
    }
    resid[b0 + tid] = v0;
    resid[b0 + tid + 256] = v1;
    float s = v0 + v1, sq = v0 * v0 + v1 * v1;
    #pragma unroll
    for (int off = 32; off; off >>= 1) {
        s  += __shfl_xor(s,  off);
        sq += __shfl_xor(sq, off);
    }
    __shared__ float ls[4], lq[4];
    int w = tid >> 6;
    if ((tid & 63) == 0) { ls[w] = s; lq[w] = sq; }
    __syncthreads();
    float S = ls[0] + ls[1] + ls[2] + ls[3];
    float Q = lq[0] + lq[1] + lq[2] + lq[3];
    float mean = S * (1.0f / H_);
    float var  = Q * (1.0f / H_) - mean * mean;
    float inv  = rsqrtf(var + 1e-5f);
    ffin_bf[b0 + tid]       = f2bf((v0 - mean) * inv);
    ffin_bf[b0 + tid + 256] = f2bf((v1 - mean) * inv);
}

template <bool DO_LN>
__global__ void reduce_ln_kernel(const float* __restrict__ part, const float* __restrict__ resid,
                                 float* __restrict__ x, bf16* __restrict__ x_bf,
                                 float* __restrict__ xn, bf16* __restrict__ xn_bf) {
    const int MN = 512 * H_;
    int row = blockIdx.x;
    int tid = threadIdx.x;
    size_t base = (size_t)row * H_;
    float v0 = resid[base + tid], v1 = resid[base + tid + 256];
    #pragma unroll
    for (int s = 0; s < 4; ++s) {
        v0 += part[(size_t)s * MN + base + tid];
        v1 += part[(size_t)s * MN + base + tid + 256];
    }
    x[base + tid] = v0;
    x[base + tid + 256] = v1;
    x_bf[base + tid]       = f2bf(v0);
    x_bf[base + tid + 256] = f2bf(v1);
    if (DO_LN) {
        float s = v0 + v1, sq = v0 * v0 + v1 * v1;
        #pragma unroll
        for (int off = 32; off; off >>= 1) {
            s  += __shfl_xor(s,  off);
            sq += __shfl_xor(sq, off);
        }
        __shared__ float ls[4], lq[4];
        int w = tid >> 6;
        if ((tid & 63) == 0) { ls[w] = s; lq[w] = sq; }
        __syncthreads();
        float S = ls[0] + ls[1] + ls[2] + ls[3];
        float Q = lq[0] + lq[1] + lq[2] + lq[3];
        float mean = S * (1.0f / H_);
        float var  = Q * (1.0f / H_) - mean * mean;
        float inv  = rsqrtf(var + 1e-5f);
        float y0 = (v0 - mean) * inv, y1 = (v1 - mean) * inv;
        xn[base + tid]       = y0;
        xn[base + tid + 256] = y1;
        xn_bf[base + tid]       = f2bf(y0);
        xn_bf[base + tid + 256] = f2bf(y1);
    }
}

// ---------------------------------------------------------------- attention
// l=0: w-row gathered from E0[adj[pair]] (8-row table, L1-resident)
template <bool GATHER>
__global__ void attn_kernel(const float* __restrict__ qkv, const bf16* __restrict__ ew,
                            const int* __restrict__ adj, bf16* __restrict__ o) {
    const float* q = qkv;
    const float* k = qkv + (size_t)512 * H_;
    const float* v = qkv + (size_t)1024 * H_;
    int bi = blockIdx.x;
    int b  = bi >> 6;
    int ty = threadIdx.y;
    int h  = blockIdx.y * 4 + ty;
    int lane = threadIdx.x;
    __shared__ float qs[4][64], as[4][64];
    qs[ty][lane] = q[(size_t)bi * H_ + h * 64 + lane];
    __syncthreads();

    int j = lane;
    int pair = bi * 64 + j;
    int aj = adj[pair];
    const float4* k4 = (const float4*)(k + (size_t)(b * 64 + j) * H_ + h * 64);
    const uint4*  w4 = (const uint4*)((GATHER ? ew + (size_t)aj * H_
                                              : ew + (size_t)pair * H_) + h * 64);
    float acc = 0.f;
    #pragma unroll
    for (int t = 0; t < 8; ++t) {
        uint4 wu = w4[t];
        float4 ka = k4[2 * t], kb = k4[2 * t + 1];
        float wf[8];
        unpack8(wu, wf);
        const float* qq = &qs[ty][t * 8];
        acc += qq[0] * (ka.x + wf[0]) + qq[1] * (ka.y + wf[1])
             + qq[2] * (ka.z + wf[2]) + qq[3] * (ka.w + wf[3])
             + qq[4] * (kb.x + wf[4]) + qq[5] * (kb.y + wf[5])
             + qq[6] * (kb.z + wf[6]) + qq[7] * (kb.w + wf[7]);
    }
    float logit = acc * INV_SCALE;
    if (aj <= 0) logit = -INFINITY;

    float m = logit;
    #pragma unroll
    for (int off = 32; off; off >>= 1) m = fmaxf(m, __shfl_xor(m, off));
    float p = expf(logit - m);
    float s = p;
    #pragma unroll
    for (int off = 32; off; off >>= 1) s += __shfl_xor(s, off);
    as[ty][lane] = p / s;
    __syncthreads();

    const float* vbase = v + (size_t)(b * 64) * H_ + h * 64;
    float oacc = 0.f;
    int d = lane;
    #pragma unroll 8
    for (int jj = 0; jj < 64; ++jj)
        oacc += as[ty][jj] * vbase[(size_t)jj * H_ + d];
    o[(size_t)bi * H_ + h * 64 + d] = __float2bfloat16(oacc);
}

// l=1/l=2: w-term combined inline from P-tables
template <int MODE>
__global__ void attn13_kernel(const float* __restrict__ qkv, const int* __restrict__ adj,
        const float* __restrict__ c0a, const float* __restrict__ c1a, const float* __restrict__ c2a,
        const float* __restrict__ c0b, const float* __restrict__ c1b, const float* __restrict__ c2b,
        const float* __restrict__ PX, const float* __restrict__ PY, const float* __restrict__ PE,
        bf16* __restrict__ o) {
    const float* q = qkv;
    const float* k = qkv + (size_t)512 * H_;
    const float* v = qkv + (size_t)1024 * H_;
    int bi = blockIdx.x;
    int b  = bi >> 6, i = bi & 63;
    int ty = threadIdx.y;
    int h  = blockIdx.y * 4 + ty;
    int lane = threadIdx.x;
    __shared__ float qs[4][64], as[4][64];
    qs[ty][lane] = q[(size_t)bi * H_ + h * 64 + lane];
    __syncthreads();

    int j = lane;
    int p = bi * 64 + j;
    int t = adj[p];
    size_t pb = (((size_t)b * 8 + h) * 64 + i) * 64;
    float acc;
    if (MODE == 1) {
        acc = c0a[p] * PE[pb + t] + c1a[p] * PX[pb + i] + c2a[p] * PX[pb + j];
    } else {
        float a0 = c0b[p];
        float AE = a0 * c0a[p], Aa = a0 * c1a[p], Ab = a0 * c2a[p];
        float Ac = c1b[p], Ad = c2b[p];
        acc = AE * PE[pb + t] + Aa * PX[pb + i] + Ab * PX[pb + j]
            + Ac * PY[pb + i] + Ad * PY[pb + j];
    }
    const float4* k4 = (const float4*)(k + (size_t)(b * 64 + j) * H_ + h * 64);
    #pragma unroll
    for (int tt = 0; tt < 8; ++tt) {
        float4 ka = k4[2 * tt], kb = k4[2 * tt + 1];
        const float* qq = &qs[ty][tt * 8];
        acc += qq[0] * ka.x + qq[1] * ka.y + qq[2] * ka.z + qq[3] * ka.w
             + qq[4] * kb.x + qq[5] * kb.y + qq[6] * kb.z + qq[7] * kb.w;
    }
    float logit = acc * INV_SCALE;
    if (t <= 0) logit = -INFINITY;

    float m = logit;
    #pragma unroll
    for (int off = 32; off; off >>= 1) m = fmaxf(m, __shfl_xor(m, off));
    float pe = expf(logit - m);
    float s = pe;
    #pragma unroll
    for (int off = 32; off; off >>= 1) s += __shfl_xor(s, off);
    as[ty][lane] = pe / s;
    __syncthreads();

    const float* vbase = v + (size_t)(b * 64) * H_ + h * 64;
    float oacc = 0.f;
    int d = lane;
    #pragma unroll 8
    for (int jj = 0; jj < 64; ++jj)
        oacc += as[ty][jj] * vbase[(size_t)jj * H_ + d];
    o[(size_t)bi * H_ + h * 64 + d] = __float2bfloat16(oacc);
}

// l=3: w-term computed inline from M-tables + coeffs (s2_assemble fused in)
__global__ void attn3s2_kernel(const float* __restrict__ qkv, const int* __restrict__ adj,
        const float* __restrict__ c0a, const float* __restrict__ c1a, const float* __restrict__ c2a,
        const float* __restrict__ c0b, const float* __restrict__ c1b, const float* __restrict__ c2b,
        const float* __restrict__ v0c, const float* __restrict__ v1c, const float* __restrict__ v2c,
        const float* __restrict__ MX, const float* __restrict__ MY,
        const float* __restrict__ MZ, const float* __restrict__ DE,
        bf16* __restrict__ o) {
    const float* q = qkv;
    const float* k = qkv + (size_t)512 * H_;
    const float* v = qkv + (size_t)1024 * H_;
    int bi = blockIdx.x;
    int b  = bi >> 6, i = bi & 63;
    int ty = threadIdx.y;
    int h  = blockIdx.y * 4 + ty;
    int lane = threadIdx.x;
    __shared__ float qs[4][64], as[4][64];
    qs[ty][lane] = q[(size_t)bi * H_ + h * 64 + lane];
    __syncthreads();

    int j = lane;
    int p = bi * 64 + j;
    int t = adj[p];
    float v0 = v0c[p];
    float q0 = v0 * c0b[p];
    float AE = q0 * c0a[p], Aa = q0 * c1a[p], Ab = q0 * c2a[p];
    float Ac = v0 * c1b[p], Ad = v0 * c2b[p];
    float Ae = v1c[p], Af = v2c[p];
    size_t rb = ((size_t)b * 512 + i * 8 + h) * 64;
    float acc = AE * DE[rb + t]
              + Aa * MX[rb + i] + Ac * MY[rb + i] + Ae * MZ[rb + i]
              + Ab * MX[rb + j] + Ad * MY[rb + j] + Af * MZ[rb + j];

    const float4* k4 = (const float4*)(k + (size_t)(b * 64 + j) * H_ + h * 64);
    #pragma unroll
    for (int tt = 0; tt < 8; ++tt) {
        float4 ka = k4[2 * tt], kb = k4[2 * tt + 1];
        const float* qq = &qs[ty][tt * 8];
        acc += qq[0] * ka.x + qq[1] * ka.y + qq[2] * ka.z + qq[3] * ka.w
             + qq[4] * kb.x + qq[5] * kb.y + qq[6] * kb.z + qq[7] * kb.w;
    }
    float logit = acc * INV_SCALE;
    if (t <= 0) logit = -INFINITY;

    float m = logit;
    #pragma unroll
    for (int off = 32; off; off >>= 1) m = fmaxf(m, __shfl_xor(m, off));
    float pe = expf(logit - m);
    float s = pe;
    #pragma unroll
    for (int off = 32; off; off >>= 1) s += __shfl_xor(s, off);
    as[ty][lane] = pe / s;
    __syncthreads();

    const float* vbase = v + (size_t)(b * 64) * H_ + h * 64;
    float oacc = 0.f;
    int d = lane;
    #pragma unroll 8
    for (int jj = 0; jj < 64; ++jj)
        oacc += as[ty][jj] * vbase[(size_t)jj * H_ + d];
    o[(size_t)bi * H_ + h * 64 + d] = __float2bfloat16(oacc);
}

// ---------------------------------------------------------------- head
__global__ void cls_part_kernel(const float* __restrict__ x, const float* __restrict__ Wout,
                                float* __restrict__ clspart) {
    int b  = blockIdx.x;
    int cb = blockIdx.y;
    int ks = blockIdx.z;
    int tid = threadIdx.x;
    int c  = cb * 64 + (tid & 63);
    int kk = tid >> 6;
    const float* xr = x + (size_t)(b * 64) * H_;
    int h0 = ks * 128 + kk * 32;
    float acc = 0.f;
    #pragma unroll
    for (int h = 0; h < 32; ++h)
        acc += xr[h0 + h] * Wout[(size_t)(h0 + h) * H_ + c];
    __shared__ float red[4][64];
    red[kk][tid & 63] = acc;
    __syncthreads();
    if (tid < 64) {
        float v = red[0][tid] + red[1][tid] + red[2][tid] + red[3][tid];
        clspart[((size_t)ks * 8 + b) * H_ + cb * 64 + tid] = v;
    }
}

__global__ void cls_pred2_kernel(const float* __restrict__ clspart,
                                 const float* __restrict__ Wpred,
                                 const float* __restrict__ bpred,
                                 float* __restrict__ out) {
    int b = blockIdx.x;
    int tid = threadIdx.x;
    __shared__ float red0[4], red1[4];
    float a0 = 0.f, a1 = 0.f;
    #pragma unroll
    for (int t = 0; t < 2; ++t) {
        int c = tid + t * 256;
        float v = clspart[((size_t)0 * 8 + b) * H_ + c]
                + clspart[((size_t)1 * 8 + b) * H_ + c]
                + clspart[((size_t)2 * 8 + b) * H_ + c]
                + clspart[((size_t)3 * 8 + b) * H_ + c];
        float tv = tanhf(v);
        a0 += tv * Wpred[c * 2 + 0];
        a1 += tv * Wpred[c * 2 + 1];
    }
    #pragma unroll
    for (int off = 32; off; off >>= 1) {
        a0 += __shfl_xor(a0, off);
        a1 += __shfl_xor(a1, off);
    }
    int w = tid >> 6;
    if ((tid & 63) == 0) { red0[w] = a0; red1[w] = a1; }
    __syncthreads();
    if (tid == 0) {
        float s0 = red0[0] + red0[1] + red0[2] + red0[3] + bpred[0];
        float s1 = red1[0] + red1[1] + red1[2] + red1[3] + bpred[1];
        float m = fmaxf(s0, s1);
        float e0 = expf(s0 - m), e1 = expf(s1 - m);
        float inv = 1.0f / (e0 + e1);
        out[b * 2 + 0] = e0 * inv;
        out[b * 2 + 1] = e1 * inv;
    }
}

// ---------------------------------------------------------------- launch
extern "C" void kernel_launch(void* const* d_in, const int* in_sizes, int n_in,
                              void* d_out, int out_size, void* d_ws, size_t ws_size,
                              hipStream_t stream) {
    const int*   ids      = (const int*)d_in[0];
    const int*   adj      = (const int*)d_in[1];
    const float* atom_emb = (const float*)d_in[2];
    const float* bond_emb = (const float*)d_in[3];
    const float* Wq     = (const float*)d_in[4];
    const float* Wk     = (const float*)d_in[5];
    const float* Wv     = (const float*)d_in[6];
    const float* Wew    = (const float*)d_in[7];
    const float* Wstack = (const float*)d_in[8];
    const float* Wf1    = (const float*)d_in[9];
    const float* Wf2    = (const float*)d_in[10];
    const float* Wout   = (const float*)d_in[11];
    const float* Wpred  = (const float*)d_in[12];
    const float* bpred  = (const float*)d_in[13];

    char* ws = (char*)d_ws;
    size_t off = 0;
    auto alloc = [&](size_t bytes) {
        size_t o = off;
        off += (bytes + 255) & ~(size_t)255;
        return o;
    };
    const size_t ROWS  = (size_t)B_ * N_;
    const size_t PAIRS = (size_t)B_ * N_ * N_;
    const size_t KN    = (size_t)H_ * H_;

    float* x       = (float*)(ws + alloc(ROWS * H_ * 4));
    float* xn      = (float*)(ws + alloc(ROWS * H_ * 4));
    bf16*  xn_bf   = (bf16*) (ws + alloc(ROWS * H_ * 2));
    bf16*  x_bf    = (bf16*) (ws + alloc(ROWS * H_ * 2));
    float* qkv     = (float*)(ws + alloc(3 * ROWS * H_ * 4));
    bf16*  o_bf    = (bf16*) (ws + alloc(ROWS * H_ * 2));
    float* resid   = (float*)(ws + alloc(ROWS * H_ * 4));
    bf16*  ffin_bf = (bf16*) (ws + alloc(ROWS * H_ * 2));
    bf16*  ffh_bf  = (bf16*) (ws + alloc(ROWS * 4 * H_ * 2));
    float* part    = (float*)(ws + alloc(4 * ROWS * H_ * 4));
    float* clspart = (float*)(ws + alloc(4 * 8 * H_ * 4));
    bf16*  ubf     = (bf16*) (ws + alloc(ROWS * 8 * 512 * 2));           // 4 MB
    float* MX      = (float*)(ws + alloc((size_t)4096 * 64 * 4));        // 1 MB each
    float* MY      = (float*)(ws + alloc((size_t)4096 * 64 * 4));
    float* MZ      = (float*)(ws + alloc((size_t)4096 * 64 * 4));
    float* DE      = (float*)(ws + alloc((size_t)4096 * 64 * 4));
    float* PT0     = (float*)(ws + alloc((size_t)4096 * 64 * 4));        // P-tables
    float* PT1     = (float*)(ws + alloc((size_t)4096 * 64 * 4));
    float* PT2     = (float*)(ws + alloc((size_t)4096 * 64 * 4));
    float* gbuf    = (float*)(ws + alloc((size_t)9 * 8 * 4096 * 4));     // Gram tables (slots 5,6 reused for l=0)
    bf16*  wc3     = (bf16*) (ws + alloc(KN * 2));
    bf16*  bond_bf = (bf16*) (ws + alloc(64 * H_ * 2));      // bond_emb bf16, rows 8..63 zero
    bf16*  E0      = (bf16*) (ws + alloc(64 * H_ * 2));      // padded to 64 rows
    bf16*  e0w1    = (bf16*) (ws + alloc(64 * H_ * 2));
    bf16*  e0w12   = (bf16*) (ws + alloc(64 * H_ * 2));
    bf16*  xw1     = (bf16*) (ws + alloc(KN * 2));
    bf16*  xw12    = (bf16*) (ws + alloc(KN * 2));
    bf16*  x2w2    = (bf16*) (ws + alloc(KN * 2));
    float* cw      = (float*)(ws + alloc(9 * PAIRS * 4));    // edge softmax coeffs
    bf16*  qkvt    = (bf16*) (ws + alloc((size_t)L_ * 3 * KN * 2));
    bf16*  ewt     = (bf16*) (ws + alloc((size_t)L_ * KN * 2));
    bf16*  stackt  = (bf16*) (ws + alloc((size_t)L_ * KN * 2));
    bf16*  f1t     = (bf16*) (ws + alloc((size_t)L_ * 4 * KN * 2));
    bf16*  f2t     = (bf16*) (ws + alloc((size_t)L_ * 4 * KN * 2));
    (void)ws_size;

    float* cw0a = cw;
    float* cw1a = cw + PAIRS;
    float* cw2a = cw + 2 * PAIRS;
    float* cw0b = cw + 3 * PAIRS;
    float* cw1b = cw + 4 * PAIRS;
    float* cw2b = cw + 5 * PAIRS;
    float* cw0c = cw + 6 * PAIRS;
    float* cw1c = cw + 7 * PAIRS;
    float* cw2c = cw + 8 * PAIRS;

    // one-shot setup: embed+LN, weight transposes (2 tiles/block), bond_bf, Wew3 cast
    setup_kernel<<<2432, 256, 0, stream>>>(ids, atom_emb, bond_emb,
                                           Wq, Wk, Wv, Wew, Wstack, Wf1, Wf2,
                                           xn, xn_bf, qkvt, ewt, stackt, f1t, f2t,
                                           bond_bf, wc3);

    for (int l = 0; l < L_; ++l) {
        if (l == 0) {
            // qkv + E0 (E0 = bond_bf @ ewt0 via MFMA)
            qkv0_e0<<<200, 256, 0, stream>>>(xn_bf, qkvt, qkv, bond_bf, ewt, E0);
            attn_kernel<true><<<dim3(512, 2), dim3(64, 4), 0, stream>>>(qkv, E0, adj, o_bf);
        } else if (l == 1) {
            // basis1 + qkv + l=0 Gram tables (G0_b, TEE)
            basis1_qkv_g0<<<273, 256, 0, stream>>>(
                x_bf, E0, ewt + KN, xw1, e0w1, xn_bf, qkvt + (size_t)3 * KN, qkv, gbuf);
            // ptables + l=0 coeff assemble (Gram-based)
            ptable1c<<<192, 256, 0, stream>>>(qkv, xw1, e0w1, PT0, PT1,
                                              adj, gbuf, cw0a, cw1a, cw2a);
            attn13_kernel<1><<<dim3(512, 2), dim3(64, 4), 0, stream>>>(
                qkv, adj, cw0a, cw1a, cw2a, nullptr, nullptr, nullptr,
                PT0, nullptr, PT1, o_bf);
        } else if (l == 2) {
            // basis2 + qkv + gram1
            basis2_qkv_g1<<<368, 256, 0, stream>>>(
                xw1, x_bf, e0w1, ewt + 2 * KN, xw12, x2w2, e0w12,
                xn_bf, qkvt + (size_t)6 * KN, qkv, gbuf);
            // ptables + coeff1
            ptable2c<<<256, 256, 0, stream>>>(
                qkv, xw12, x2w2, e0w12, PT0, PT1, PT2,
                adj, cw0a, cw1a, cw2a, gbuf, cw0b, cw1b, cw2b);
            attn13_kernel<2><<<dim3(512, 2), dim3(64, 4), 0, stream>>>(
                qkv, adj, cw0a, cw1a, cw2a, cw0b, cw1b, cw2b,
                PT0, PT1, PT2, o_bf);
        } else {
            // qkv + gram2
            l3qkv_g2<<<264, 256, 0, stream>>>(
                xn_bf, qkvt + (size_t)9 * KN, qkv, xw12, x2w2, e0w12, x_bf, gbuf);
            // u + coeff2
            u_c2<<<576, 256, 0, stream>>>(
                qkv, wc3, ubf, adj, cw0a, cw1a, cw2a, cw0b, cw1b, cw2b,
                gbuf, cw0c, cw1c, cw2c);
            mbuf_gemm<<<dim3(8, 8, 4), 256, 0, stream>>>(ubf, xw12, x2w2, x_bf, e0w12,
                                                         MX, MY, MZ, DE);
            attn3s2_kernel<<<dim3(512, 2), dim3(64, 4), 0, stream>>>(
                qkv, adj, cw0a, cw1a, cw2a, cw0b, cw1b, cw2b, cw0c, cw1c, cw2c,
                MX, MY, MZ, DE, o_bf);
        }

        mfma_gemm_s<0, true><<<dim3(8, 8, 4), 256, 0, stream>>>(
            o_bf, stackt + (size_t)l * KN, part, nullptr, 512, 512, 512);
        reduce_stack_ln<<<512, 256, 0, stream>>>(part, xn, resid, ffin_bf);
        mfma_gemm_s<2, false><<<dim3(8, 32), 256, 0, stream>>>(
            ffin_bf, f1t + (size_t)l * 4 * KN, ffh_bf, nullptr, 512, 2048, 512);
        mfma_gemm_s<0, true><<<dim3(8, 8, 4), 256, 0, stream>>>(
            ffh_bf, f2t + (size_t)l * 4 * KN, part, nullptr, 512, 512, 2048);
        if (l < L_ - 1)
            reduce_ln_kernel<true><<<512, 256, 0, stream>>>(part, resid, x, x_bf, xn, xn_bf);
        else
            reduce_ln_kernel<false><<<512, 256, 0, stream>>>(part, resid, x, x_bf, xn, xn_bf);
    }

    cls_part_kernel<<<dim3(8, 8, 4), 256, 0, stream>>>(x, Wout, clspart);
    cls_pred2_kernel<<<8, 256, 0, stream>>>(clspart, Wpred, bpred, (float*)d_out);
}